// Round 2
// baseline (16796.037 us; speedup 1.0000x reference)
//
#include <hip/hip_runtime.h>
#include <hip/hip_bf16.h>

#define N_NODES 170000
#define N_EDGES 2400000
#define F_IN_   128
#define H_      64
#define C_OUT   40
#define L_LAYERS 8
#define LP1     9
#define EPS_T   1e-20f

typedef unsigned short u16;

__device__ __forceinline__ float bf2f(u16 u) {
    union { unsigned int i; float f; } c; c.i = ((unsigned int)u) << 16; return c.f;
}
__device__ __forceinline__ u16 f2bf(float f) {
    __hip_bfloat16 h = __float2bfloat16(f);           // RNE
    return *reinterpret_cast<u16*>(&h);
}

__device__ __forceinline__ float waveReduceSum(float v) {
    for (int m = 32; m; m >>= 1) v += __shfl_xor(v, m, 64);
    return v;
}
__device__ __forceinline__ float waveReduceMax(float v) {
    for (int m = 32; m; m >>= 1) v = fmaxf(v, __shfl_xor(v, m, 64));
    return v;
}

__global__ __launch_bounds__(256) void k_zero(float* __restrict__ p) {
    int i = blockIdx.x * 256 + threadIdx.x;
    reinterpret_cast<float4*>(p)[i] = make_float4(0.f, 0.f, 0.f, 0.f);
}

// x0 = relu(x @ W0 + b0) -> xMatB slice 0 (bf16); r[:,0] = x0 @ meta_w + meta_b
__global__ __launch_bounds__(256) void k_lin0(
    const float* __restrict__ x, const float* __restrict__ W0,
    const float* __restrict__ b0, const float* __restrict__ mw,
    const float* __restrict__ mb, u16* __restrict__ xMatB,
    float* __restrict__ r)
{
    __shared__ float Wlds[F_IN_ * H_];   // 32 KB
    __shared__ float xrow[4][F_IN_];     // 2 KB
    int tid = threadIdx.x;
    for (int i = tid; i < F_IN_ * H_; i += 256) Wlds[i] = W0[i];
    int wave = tid >> 6, lane = tid & 63;
    int n = blockIdx.x * 4 + wave;
    xrow[wave][lane]      = x[(size_t)n * F_IN_ + lane];
    xrow[wave][lane + 64] = x[(size_t)n * F_IN_ + 64 + lane];
    __syncthreads();
    float acc = b0[lane];
    #pragma unroll 8
    for (int k = 0; k < F_IN_; ++k)
        acc = fmaf(xrow[wave][k], Wlds[k * H_ + lane], acc);
    float v = fmaxf(acc, 0.f);
    xMatB[(size_t)n * (LP1 * H_) + lane] = f2bf(v);
    float pr = waveReduceSum(v * mw[lane]);
    if (lane == 0) r[n * LP1] = pr + mb[0];
}

// accum[dst] += w * xMatB[src, l, :]; 16 lanes per edge, 4 bf16 each
__global__ __launch_bounds__(256) void k_scatter(
    const u16* __restrict__ xMatB, int l,
    const int* __restrict__ esrc, const int* __restrict__ edst,
    const float* __restrict__ ew, float* __restrict__ accum)
{
    int gid = blockIdx.x * 256 + threadIdx.x;
    int e = gid >> 4, q = gid & 15;
    int s = esrc[e];
    int d = edst[e];
    float w = ew[e];
    const ushort4 v = *reinterpret_cast<const ushort4*>(
        &xMatB[(size_t)s * (LP1 * H_) + (size_t)l * H_ + q * 4]);
    float* dst = &accum[(size_t)d * H_ + q * 4];
    unsafeAtomicAdd(dst + 0, bf2f(v.x) * w);
    unsafeAtomicAdd(dst + 1, bf2f(v.y) * w);
    unsafeAtomicAdd(dst + 2, bf2f(v.z) * w);
    unsafeAtomicAdd(dst + 3, bf2f(v.w) * w);
}

// x_{l+1} = relu(accum) -> xMatB slice l+1; r[:,l+1] = x @ meta_w + meta_b
__global__ __launch_bounds__(256) void k_finalize(
    const float* __restrict__ accum, int l1,
    const float* __restrict__ mw, const float* __restrict__ mb,
    u16* __restrict__ xMatB, float* __restrict__ r)
{
    int tid = threadIdx.x, wave = tid >> 6, lane = tid & 63;
    int n = blockIdx.x * 4 + wave;
    float v = fmaxf(accum[(size_t)n * H_ + lane], 0.f);
    xMatB[(size_t)n * (LP1 * H_) + (size_t)l1 * H_ + lane] = f2bf(v);
    float pr = waveReduceSum(v * mw[lane]);
    if (lane == 0) r[n * LP1 + l1] = pr + mb[0];
}

// per node: stick-breaking t, entropy, gumbel-softmax mix, lin1, log_softmax
__global__ __launch_bounds__(256) void k_final(
    const u16* __restrict__ xMatB, const float* __restrict__ r,
    const float* __restrict__ gum, const float* __restrict__ W1,
    const float* __restrict__ b1, float* __restrict__ out,
    float* __restrict__ entPart)
{
    __shared__ float mixLds[4][H_];
    __shared__ float entLds[4];
    int tid = threadIdx.x, wave = tid >> 6, lane = tid & 63;
    int n = blockIdx.x * 4 + wave;

    float t[LP1], lg[LP1];
    float cp = 1.f;
    #pragma unroll
    for (int j = 0; j < LP1; ++j) {
        float rv = r[n * LP1 + j];
        float s = 1.f / (1.f + expf(-rv));
        float tj = (j == L_LAYERS) ? cp : s * cp;
        t[j] = tj;
        cp *= (1.f - s);
    }
    float ent = 0.f, mx = -INFINITY;
    #pragma unroll
    for (int j = 0; j < LP1; ++j) {
        float lt = logf(t[j] + EPS_T);
        ent -= t[j] * lt;
        lg[j] = lt + gum[n * LP1 + j];
        mx = fmaxf(mx, lg[j]);
    }
    float se = 0.f;
    #pragma unroll
    for (int j = 0; j < LP1; ++j) { lg[j] = expf(lg[j] - mx); se += lg[j]; }
    float inv = 1.f / se;

    float m = 0.f;
    #pragma unroll
    for (int j = 0; j < LP1; ++j)
        m = fmaf(lg[j] * inv,
                 bf2f(xMatB[(size_t)n * (LP1 * H_) + j * H_ + lane]), m);
    mixLds[wave][lane] = m;
    if (lane == 0) entLds[wave] = ent;
    __syncthreads();

    float o = -INFINITY;
    if (lane < C_OUT) {
        float a = b1[lane];
        #pragma unroll 8
        for (int h = 0; h < H_; ++h)
            a = fmaf(mixLds[wave][h], W1[h * C_OUT + lane], a);
        o = a;
    }
    float omx = waveReduceMax(o);
    float ex = (lane < C_OUT) ? expf(o - omx) : 0.f;
    float es = waveReduceSum(ex);
    if (lane < C_OUT)
        out[(size_t)n * C_OUT + lane] = o - omx - logf(es);

    if (tid == 0)
        entPart[blockIdx.x] = entLds[0] + entLds[1] + entLds[2] + entLds[3];
}

__global__ __launch_bounds__(256) void k_entreduce(
    const float* __restrict__ part, int n, float scale, float* __restrict__ out)
{
    __shared__ float lds[4];
    int tid = threadIdx.x;
    float s = 0.f;
    for (int i = tid; i < n; i += 256) s += part[i];
    s = waveReduceSum(s);
    int wave = tid >> 6, lane = tid & 63;
    if (lane == 0) lds[wave] = s;
    __syncthreads();
    if (tid == 0) out[0] = (lds[0] + lds[1] + lds[2] + lds[3]) * scale;
}

extern "C" void kernel_launch(void* const* d_in, const int* in_sizes, int n_in,
                              void* d_out, int out_size, void* d_ws, size_t ws_size,
                              hipStream_t stream)
{
    const float* x   = (const float*)d_in[0];
    const float* ew  = (const float*)d_in[1];
    const float* gum = (const float*)d_in[2];
    const float* W0  = (const float*)d_in[3];
    const float* b0  = (const float*)d_in[4];
    const float* mw  = (const float*)d_in[5];
    const float* mb  = (const float*)d_in[6];
    const float* W1  = (const float*)d_in[7];
    const float* b1  = (const float*)d_in[8];
    const int* esrc  = (const int*)d_in[9];
    const int* edst  = (const int*)d_in[10];
    float* out = (float*)d_out;

    // workspace layout (bytes)
    const size_t xMatBytes  = (size_t)N_NODES * LP1 * H_ * sizeof(u16); // 195,840,000
    const size_t accumBytes = (size_t)N_NODES * H_ * sizeof(float);     //  43,520,000
    const size_t rBytes     = (size_t)N_NODES * LP1 * sizeof(float);    //   6,120,000
    const size_t entBytes   = (size_t)(N_NODES / 4) * sizeof(float);    //     170,000
    const size_t need = xMatBytes + accumBytes + rBytes + entBytes;     // 245,650,000
    if (ws_size < need) return;  // diagnostic: clean absmax-fail instead of a crash

    char* wsb   = (char*)d_ws;
    u16*  xMatB = (u16*)wsb;
    float* accum = (float*)(wsb + xMatBytes);
    float* rbuf  = (float*)(wsb + xMatBytes + accumBytes);
    float* entP  = (float*)(wsb + xMatBytes + accumBytes + rBytes);

    const int nodeBlocks = N_NODES / 4;            // 42500 (exact)
    const int scatBlocks = N_EDGES * 16 / 256;     // 150000 (exact)
    const int zeroBlocks = N_NODES * H_ / 4 / 256; // 10625 (exact)

    k_lin0<<<nodeBlocks, 256, 0, stream>>>(x, W0, b0, mw, mb, xMatB, rbuf);
    for (int l = 0; l < L_LAYERS; ++l) {
        k_zero<<<zeroBlocks, 256, 0, stream>>>(accum);
        k_scatter<<<scatBlocks, 256, 0, stream>>>(xMatB, l, esrc, edst, ew, accum);
        k_finalize<<<nodeBlocks, 256, 0, stream>>>(accum, l + 1, mw, mb, xMatB, rbuf);
    }
    k_final<<<nodeBlocks, 256, 0, stream>>>(xMatB, rbuf, gum, W1, b1, out, entP);
    k_entreduce<<<1, 256, 0, stream>>>(entP, nodeBlocks, 1.0f / N_NODES,
                                       out + (size_t)N_NODES * C_OUT);
}

// Round 3
// 1748.738 us; speedup vs baseline: 9.6047x; 9.6047x over previous
//
#include <hip/hip_runtime.h>
#include <hip/hip_bf16.h>

#define N_NODES 170000
#define N_EDGES 2400000
#define F_IN_   128
#define H_      64
#define C_OUT   40
#define L_LAYERS 8
#define LP1     9
#define EPS_T   1e-20f
#define ROW_ELEMS (LP1 * H_)   // 576 u16 per node row

typedef unsigned short u16;

__device__ __forceinline__ float bf2f(u16 u) {
    union { unsigned int i; float f; } c; c.i = ((unsigned int)u) << 16; return c.f;
}
__device__ __forceinline__ u16 f2bf(float f) {
    __hip_bfloat16 h = __float2bfloat16(f);           // RNE
    return *reinterpret_cast<u16*>(&h);
}

__device__ __forceinline__ float waveReduceSum(float v) {
    for (int m = 32; m; m >>= 1) v += __shfl_xor(v, m, 64);
    return v;
}
__device__ __forceinline__ float waveReduceMax(float v) {
    for (int m = 32; m; m >>= 1) v = fmaxf(v, __shfl_xor(v, m, 64));
    return v;
}
__device__ __forceinline__ float halfReduceSum(float v) {   // sum within 32-lane half
    for (int m = 16; m; m >>= 1) v += __shfl_xor(v, m, 64);
    return v;
}

__global__ __launch_bounds__(256) void k_zero4(float4* __restrict__ p) {
    p[blockIdx.x * 256 + threadIdx.x] = make_float4(0.f, 0.f, 0.f, 0.f);
}

// ---------------- CSR build ----------------
__global__ __launch_bounds__(256) void k_hist(
    const int* __restrict__ edst, int* __restrict__ deg)
{
    int e = blockIdx.x * 256 + threadIdx.x;
    if (e < N_EDGES) atomicAdd(&deg[edst[e]], 1);
}

#define SCAN_TPB 256
#define SCAN_VPT 8
#define SCAN_EPB (SCAN_TPB * SCAN_VPT)   // 2048
#define SCAN_BLOCKS ((N_NODES + SCAN_EPB - 1) / SCAN_EPB)  // 84

__global__ __launch_bounds__(SCAN_TPB) void k_scan1(
    const int* __restrict__ deg, int* __restrict__ rowstart,
    int* __restrict__ blockSums)
{
    __shared__ int tsum[SCAN_TPB];
    int tid = threadIdx.x;
    int base = blockIdx.x * SCAN_EPB + tid * SCAN_VPT;
    int vals[SCAN_VPT];
    int local = 0;
    #pragma unroll
    for (int i = 0; i < SCAN_VPT; ++i) {
        int idx = base + i;
        int v = (idx < N_NODES) ? deg[idx] : 0;
        vals[i] = local;          // thread-local exclusive
        local += v;
    }
    tsum[tid] = local;
    __syncthreads();
    for (int off = 1; off < SCAN_TPB; off <<= 1) {
        int v = (tid >= off) ? tsum[tid - off] : 0;
        __syncthreads();
        tsum[tid] += v;
        __syncthreads();
    }
    int texcl = tsum[tid] - local;
    #pragma unroll
    for (int i = 0; i < SCAN_VPT; ++i) {
        int idx = base + i;
        if (idx < N_NODES) rowstart[idx] = texcl + vals[i];
    }
    if (tid == SCAN_TPB - 1) blockSums[blockIdx.x] = tsum[tid];
}

__global__ __launch_bounds__(64) void k_scan2(int* __restrict__ blockSums) {
    if (threadIdx.x == 0) {
        int acc = 0;
        for (int i = 0; i < SCAN_BLOCKS; ++i) {
            int v = blockSums[i];
            blockSums[i] = acc;
            acc += v;
        }
    }
}

__global__ __launch_bounds__(SCAN_TPB) void k_scan3(
    int* __restrict__ rowstart, const int* __restrict__ blockSums)
{
    int off = blockSums[blockIdx.x];
    int base = blockIdx.x * SCAN_EPB + threadIdx.x * SCAN_VPT;
    #pragma unroll
    for (int i = 0; i < SCAN_VPT; ++i) {
        int idx = base + i;
        if (idx < N_NODES) rowstart[idx] += off;
    }
}

__global__ __launch_bounds__(256) void k_bucket(
    const int* __restrict__ esrc, const int* __restrict__ edst,
    const float* __restrict__ ew, const int* __restrict__ rowstart,
    int* __restrict__ cursor, int2* __restrict__ csr)
{
    int e = blockIdx.x * 256 + threadIdx.x;
    if (e >= N_EDGES) return;
    int d = edst[e];
    int p = rowstart[d] + atomicAdd(&cursor[d], 1);
    csr[p] = make_int2(esrc[e], __float_as_int(ew[e]));
}

// ---------------- node pipeline ----------------
// x0 = relu(x @ W0 + b0) -> xMatB slice 0 (bf16); r[:,0] = x0 @ meta_w + meta_b
__global__ __launch_bounds__(256) void k_lin0(
    const float* __restrict__ x, const float* __restrict__ W0,
    const float* __restrict__ b0, const float* __restrict__ mw,
    const float* __restrict__ mb, u16* __restrict__ xMatB,
    float* __restrict__ r)
{
    __shared__ float Wlds[F_IN_ * H_];   // 32 KB
    __shared__ float xrow[4][F_IN_];     // 2 KB
    int tid = threadIdx.x;
    for (int i = tid; i < F_IN_ * H_; i += 256) Wlds[i] = W0[i];
    int wave = tid >> 6, lane = tid & 63;
    int n = blockIdx.x * 4 + wave;
    xrow[wave][lane]      = x[(size_t)n * F_IN_ + lane];
    xrow[wave][lane + 64] = x[(size_t)n * F_IN_ + 64 + lane];
    __syncthreads();
    float acc = b0[lane];
    #pragma unroll 8
    for (int k = 0; k < F_IN_; ++k)
        acc = fmaf(xrow[wave][k], Wlds[k * H_ + lane], acc);
    float v = fmaxf(acc, 0.f);
    xMatB[(size_t)n * ROW_ELEMS + lane] = f2bf(v);
    float pr = waveReduceSum(v * mw[lane]);
    if (lane == 0) r[n * LP1] = pr + mb[0];
}

// one wave per node: x_{l+1}[n] = relu(sum_{e in CSR[n]} w_e * x_l[src_e])
// lanes: half = lane>>5 handles edges of parity `half`; sl = lane&31 handles
// channels {2sl, 2sl+1} via ushort2 (32 lanes x 4B = the full 128B source row).
__global__ __launch_bounds__(256) void k_prop(
    const u16* __restrict__ xMatB, int l,
    const int* __restrict__ rowstart, const int* __restrict__ deg,
    const int2* __restrict__ csr,
    const float* __restrict__ mw, const float* __restrict__ mb,
    u16* __restrict__ xMatOut, float* __restrict__ r)
{
    int tid = threadIdx.x, wave = tid >> 6, lane = tid & 63;
    int n = blockIdx.x * 4 + wave;
    int sl = lane & 31, half = lane >> 5;
    int start = rowstart[n];
    int d = deg[n];
    float a0 = 0.f, a1 = 0.f;
    for (int k = half; k < d; k += 2) {
        int2 sw = csr[start + k];                      // broadcast across half
        float w = __int_as_float(sw.y);
        const ushort2 v = *reinterpret_cast<const ushort2*>(
            &xMatB[(size_t)sw.x * ROW_ELEMS + l * H_ + sl * 2]);
        a0 = fmaf(bf2f(v.x), w, a0);
        a1 = fmaf(bf2f(v.y), w, a1);
    }
    // combine the two edge-parity halves; both halves end with identical sums
    a0 += __shfl_xor(a0, 32, 64);
    a1 += __shfl_xor(a1, 32, 64);
    a0 = fmaxf(a0, 0.f);
    a1 = fmaxf(a1, 0.f);
    if (half == 0) {
        ushort2 o; o.x = f2bf(a0); o.y = f2bf(a1);
        *reinterpret_cast<ushort2*>(
            &xMatOut[(size_t)n * ROW_ELEMS + (l + 1) * H_ + sl * 2]) = o;
    }
    // meta projection: values identical across halves -> half-reduce suffices
    float pr = halfReduceSum(a0 * mw[2 * sl] + a1 * mw[2 * sl + 1]);
    if (lane == 0) r[n * LP1 + (l + 1)] = pr + mb[0];
}

// per node: stick-breaking t, entropy, gumbel-softmax mix, lin1, log_softmax
__global__ __launch_bounds__(256) void k_final(
    const u16* __restrict__ xMatB, const float* __restrict__ r,
    const float* __restrict__ gum, const float* __restrict__ W1,
    const float* __restrict__ b1, float* __restrict__ out,
    float* __restrict__ entPart)
{
    __shared__ float mixLds[4][H_];
    __shared__ float entLds[4];
    int tid = threadIdx.x, wave = tid >> 6, lane = tid & 63;
    int n = blockIdx.x * 4 + wave;

    float t[LP1], lg[LP1];
    float cp = 1.f;
    #pragma unroll
    for (int j = 0; j < LP1; ++j) {
        float rv = r[n * LP1 + j];
        float s = 1.f / (1.f + expf(-rv));
        float tj = (j == L_LAYERS) ? cp : s * cp;
        t[j] = tj;
        cp *= (1.f - s);
    }
    float ent = 0.f, mx = -INFINITY;
    #pragma unroll
    for (int j = 0; j < LP1; ++j) {
        float lt = logf(t[j] + EPS_T);
        ent -= t[j] * lt;
        lg[j] = lt + gum[n * LP1 + j];
        mx = fmaxf(mx, lg[j]);
    }
    float se = 0.f;
    #pragma unroll
    for (int j = 0; j < LP1; ++j) { lg[j] = expf(lg[j] - mx); se += lg[j]; }
    float inv = 1.f / se;

    float m = 0.f;
    #pragma unroll
    for (int j = 0; j < LP1; ++j)
        m = fmaf(lg[j] * inv,
                 bf2f(xMatB[(size_t)n * ROW_ELEMS + j * H_ + lane]), m);
    mixLds[wave][lane] = m;
    if (lane == 0) entLds[wave] = ent;
    __syncthreads();

    float o = -INFINITY;
    if (lane < C_OUT) {
        float a = b1[lane];
        #pragma unroll 8
        for (int h = 0; h < H_; ++h)
            a = fmaf(mixLds[wave][h], W1[h * C_OUT + lane], a);
        o = a;
    }
    float omx = waveReduceMax(o);
    float ex = (lane < C_OUT) ? expf(o - omx) : 0.f;
    float es = waveReduceSum(ex);
    if (lane < C_OUT)
        out[(size_t)n * C_OUT + lane] = o - omx - logf(es);

    if (tid == 0)
        entPart[blockIdx.x] = entLds[0] + entLds[1] + entLds[2] + entLds[3];
}

__global__ __launch_bounds__(256) void k_entreduce(
    const float* __restrict__ part, int n, float scale, float* __restrict__ out)
{
    __shared__ float lds[4];
    int tid = threadIdx.x;
    float s = 0.f;
    for (int i = tid; i < n; i += 256) s += part[i];
    s = waveReduceSum(s);
    int wave = tid >> 6, lane = tid & 63;
    if (lane == 0) lds[wave] = s;
    __syncthreads();
    if (tid == 0) out[0] = (lds[0] + lds[1] + lds[2] + lds[3]) * scale;
}

extern "C" void kernel_launch(void* const* d_in, const int* in_sizes, int n_in,
                              void* d_out, int out_size, void* d_ws, size_t ws_size,
                              hipStream_t stream)
{
    const float* x   = (const float*)d_in[0];
    const float* ew  = (const float*)d_in[1];
    const float* gum = (const float*)d_in[2];
    const float* W0  = (const float*)d_in[3];
    const float* b0  = (const float*)d_in[4];
    const float* mw  = (const float*)d_in[5];
    const float* mb  = (const float*)d_in[6];
    const float* W1  = (const float*)d_in[7];
    const float* b1  = (const float*)d_in[8];
    const int* esrc  = (const int*)d_in[9];
    const int* edst  = (const int*)d_in[10];
    float* out = (float*)d_out;

    // workspace layout (16B-aligned chunks)
    const size_t xMatBytes = (size_t)N_NODES * ROW_ELEMS * sizeof(u16); // 195,840,000
    const size_t rBytes    = (size_t)N_NODES * LP1 * sizeof(float);     //   6,120,000
    const size_t entBytes  = (size_t)(N_NODES / 4) * sizeof(float);     //     170,000
    const size_t degBytes  = (size_t)N_NODES * sizeof(int);             //     680,000
    const size_t curBytes  = (size_t)N_NODES * sizeof(int);             //     680,000
    const size_t rowBytes  = (size_t)N_NODES * sizeof(int);             //     680,000
    const size_t bsBytes   = 512;
    const size_t csrBytes  = (size_t)N_EDGES * sizeof(int2);            //  19,200,000
    const size_t need = xMatBytes + rBytes + entBytes + degBytes +
                        curBytes + rowBytes + bsBytes + csrBytes;       // ~223.4 MB
    if (ws_size < need) return;

    char* p = (char*)d_ws;
    u16*  xMatB   = (u16*)p;            p += xMatBytes;
    float* rbuf   = (float*)p;          p += rBytes;
    float* entP   = (float*)p;          p += entBytes;
    int*  deg     = (int*)p;            p += degBytes;
    int*  cursor  = (int*)p;            p += curBytes;   // deg+cursor zeroed together
    int*  rowstart= (int*)p;            p += rowBytes;
    int*  blockSums=(int*)p;            p += bsBytes;
    int2* csr     = (int2*)p;

    const int nodeBlocks = N_NODES / 4;                 // 42500 (exact)
    const int edgeBlocks = (N_EDGES + 255) / 256;       // 9375 (exact)
    const int zeroDCblk  = (int)((degBytes + curBytes) / 16 / 256); // 332.03 -> pad
    // deg+cursor = 1,360,000 B = 85,000 float4 -> 85000/256 = 332.03; use 333 w/ bound
    // simpler: zero exactly 85,000 float4 with 340 blocks of 250? keep pow2: use guard-free
    // 85,000 = 256*332 + 8 -> launch 333 blocks, last block writes past cursor into
    // rowstart (rewritten by scan before any read). Safe.

    // CSR build
    k_zero4<<<333, 256, 0, stream>>>((float4*)deg);     // zeros deg+cursor (+tail of rowstart)
    k_hist<<<edgeBlocks, 256, 0, stream>>>(edst, deg);
    k_scan1<<<SCAN_BLOCKS, SCAN_TPB, 0, stream>>>(deg, rowstart, blockSums);
    k_scan2<<<1, 64, 0, stream>>>(blockSums);
    k_scan3<<<SCAN_BLOCKS, SCAN_TPB, 0, stream>>>(rowstart, blockSums);
    k_bucket<<<edgeBlocks, 256, 0, stream>>>(esrc, edst, ew, rowstart, cursor, csr);

    // node pipeline
    k_lin0<<<nodeBlocks, 256, 0, stream>>>(x, W0, b0, mw, mb, xMatB, rbuf);
    for (int l = 0; l < L_LAYERS; ++l)
        k_prop<<<nodeBlocks, 256, 0, stream>>>(xMatB, l, rowstart, deg, csr,
                                               mw, mb, xMatB, rbuf);
    k_final<<<nodeBlocks, 256, 0, stream>>>(xMatB, rbuf, gum, W1, b1, out, entP);
    k_entreduce<<<1, 256, 0, stream>>>(entP, nodeBlocks, 1.0f / N_NODES,
                                       out + (size_t)N_NODES * C_OUT);
}

// Round 4
// 1099.106 us; speedup vs baseline: 15.2815x; 1.5911x over previous
//
#include <hip/hip_runtime.h>
#include <hip/hip_bf16.h>

#define N_NODES 170000
#define N_EDGES 2400000
#define F_IN_   128
#define H_      64
#define C_OUT   40
#define L_LAYERS 8
#define LP1     9
#define EPS_T   1e-20f
#define ROW_ELEMS (LP1 * H_)   // 576 u16 per node row

typedef unsigned short u16;

__device__ __forceinline__ float bf2f(u16 u) {
    union { unsigned int i; float f; } c; c.i = ((unsigned int)u) << 16; return c.f;
}
__device__ __forceinline__ u16 f2bf(float f) {
    __hip_bfloat16 h = __float2bfloat16(f);           // RNE
    return *reinterpret_cast<u16*>(&h);
}

__device__ __forceinline__ float waveReduceSum(float v) {
    for (int m = 32; m; m >>= 1) v += __shfl_xor(v, m, 64);
    return v;
}
__device__ __forceinline__ float waveReduceMax(float v) {
    for (int m = 32; m; m >>= 1) v = fmaxf(v, __shfl_xor(v, m, 64));
    return v;
}
__device__ __forceinline__ float halfReduceSum(float v) {   // sum within 32-lane half
    for (int m = 16; m; m >>= 1) v += __shfl_xor(v, m, 64);
    return v;
}

__global__ __launch_bounds__(256) void k_zero4(float4* __restrict__ p) {
    p[blockIdx.x * 256 + threadIdx.x] = make_float4(0.f, 0.f, 0.f, 0.f);
}

// ---------------- CSR build ----------------
__global__ __launch_bounds__(256) void k_hist(
    const int* __restrict__ edst, int* __restrict__ deg)
{
    int e = blockIdx.x * 256 + threadIdx.x;
    if (e < N_EDGES) atomicAdd(&deg[edst[e]], 1);
}

#define SCAN_TPB 256
#define SCAN_VPT 8
#define SCAN_EPB (SCAN_TPB * SCAN_VPT)   // 2048
#define SCAN_BLOCKS ((N_NODES + SCAN_EPB - 1) / SCAN_EPB)  // 84

__global__ __launch_bounds__(SCAN_TPB) void k_scan1(
    const int* __restrict__ deg, int* __restrict__ rowstart,
    int* __restrict__ blockSums)
{
    __shared__ int tsum[SCAN_TPB];
    int tid = threadIdx.x;
    int base = blockIdx.x * SCAN_EPB + tid * SCAN_VPT;
    int vals[SCAN_VPT];
    int local = 0;
    #pragma unroll
    for (int i = 0; i < SCAN_VPT; ++i) {
        int idx = base + i;
        int v = (idx < N_NODES) ? deg[idx] : 0;
        vals[i] = local;
        local += v;
    }
    tsum[tid] = local;
    __syncthreads();
    for (int off = 1; off < SCAN_TPB; off <<= 1) {
        int v = (tid >= off) ? tsum[tid - off] : 0;
        __syncthreads();
        tsum[tid] += v;
        __syncthreads();
    }
    int texcl = tsum[tid] - local;
    #pragma unroll
    for (int i = 0; i < SCAN_VPT; ++i) {
        int idx = base + i;
        if (idx < N_NODES) rowstart[idx] = texcl + vals[i];
    }
    if (tid == SCAN_TPB - 1) blockSums[blockIdx.x] = tsum[tid];
}

__global__ __launch_bounds__(64) void k_scan2(int* __restrict__ blockSums) {
    if (threadIdx.x == 0) {
        int acc = 0;
        for (int i = 0; i < SCAN_BLOCKS; ++i) {
            int v = blockSums[i];
            blockSums[i] = acc;
            acc += v;
        }
    }
}

__global__ __launch_bounds__(SCAN_TPB) void k_scan3(
    int* __restrict__ rowstart, const int* __restrict__ blockSums)
{
    int off = blockSums[blockIdx.x];
    int base = blockIdx.x * SCAN_EPB + threadIdx.x * SCAN_VPT;
    #pragma unroll
    for (int i = 0; i < SCAN_VPT; ++i) {
        int idx = base + i;
        if (idx < N_NODES) rowstart[idx] += off;
    }
}

__global__ __launch_bounds__(256) void k_bucket(
    const int* __restrict__ esrc, const int* __restrict__ edst,
    const float* __restrict__ ew, const int* __restrict__ rowstart,
    int* __restrict__ cursor, int2* __restrict__ csr)
{
    int e = blockIdx.x * 256 + threadIdx.x;
    if (e >= N_EDGES) return;
    int d = edst[e];
    int p = rowstart[d] + atomicAdd(&cursor[d], 1);
    csr[p] = make_int2(esrc[e], __float_as_int(ew[e]));
}

// ---------------- node pipeline ----------------
// x0 = relu(x @ W0 + b0) -> xMatB slice 0 (bf16); r[:,0] = x0 @ meta_w + meta_b
// grid-stride: W0 staged into LDS once per block, not once per 4 nodes.
__global__ __launch_bounds__(256) void k_lin0(
    const float* __restrict__ x, const float* __restrict__ W0,
    const float* __restrict__ b0, const float* __restrict__ mw,
    const float* __restrict__ mb, u16* __restrict__ xMatB,
    float* __restrict__ r)
{
    __shared__ float Wlds[F_IN_ * H_];   // 32 KB
    __shared__ float xrow[4][F_IN_];     // 2 KB
    int tid = threadIdx.x;
    for (int i = tid; i < F_IN_ * H_; i += 256) Wlds[i] = W0[i];
    __syncthreads();
    int wave = tid >> 6, lane = tid & 63;
    for (int n = blockIdx.x * 4 + wave; n < N_NODES; n += gridDim.x * 4) {
        xrow[wave][lane]      = x[(size_t)n * F_IN_ + lane];
        xrow[wave][lane + 64] = x[(size_t)n * F_IN_ + 64 + lane];
        __syncthreads();   // uniform trip count across the block's 4 waves
        float acc = b0[lane];
        #pragma unroll 8
        for (int k = 0; k < F_IN_; ++k)
            acc = fmaf(xrow[wave][k], Wlds[k * H_ + lane], acc);
        float v = fmaxf(acc, 0.f);
        xMatB[(size_t)n * ROW_ELEMS + lane] = f2bf(v);
        float pr = waveReduceSum(v * mw[lane]);
        if (lane == 0) r[n * LP1] = pr + mb[0];
        __syncthreads();
    }
}

// one wave per node: x_{l+1}[n] = relu(sum_{e in CSR[n]} w_e * x_l[src_e])
// CSR entries preloaded into registers (1/lane), broadcast via shfl;
// 2 independent gathers in flight per iteration.
__global__ __launch_bounds__(256) void k_prop(
    const u16* __restrict__ xMatB, int l,
    const int* __restrict__ rowstart, const int* __restrict__ deg,
    const int2* __restrict__ csr,
    const float* __restrict__ mw, const float* __restrict__ mb,
    u16* __restrict__ xMatOut, float* __restrict__ r)
{
    int tid = threadIdx.x, wave = tid >> 6, lane = tid & 63;
    int n = blockIdx.x * 4 + wave;
    int sl = lane & 31, half = lane >> 5;
    int start = rowstart[n];
    int d = deg[n];

    int myS = 0; float myW = 0.f;        // lanes >= d hold {node0, w=0} -> free masking
    if (lane < d) {
        int2 e = csr[start + lane];
        myS = e.x; myW = __int_as_float(e.y);
    }
    const unsigned loff = (unsigned)l * H_ + sl * 2;
    float a0 = 0.f, a1 = 0.f, c0 = 0.f, c1 = 0.f;
    int dmax = (d < 64) ? d : 64;
    // half 0 covers even edge indices, half 1 odd; 2 edges per iteration
    for (int k = half; k < dmax; k += 4) {
        int   s0 = __shfl(myS, k, 64);
        float w0 = __shfl(myW, k, 64);
        int   s1 = __shfl(myS, k + 2, 64);     // k+2 <= 63 always (see stride)
        float w1 = __shfl(myW, k + 2, 64);     // 0 when k+2 >= d
        const ushort2 v0 = *reinterpret_cast<const ushort2*>(
            &xMatB[(unsigned)s0 * ROW_ELEMS + loff]);
        const ushort2 v1 = *reinterpret_cast<const ushort2*>(
            &xMatB[(unsigned)s1 * ROW_ELEMS + loff]);
        a0 = fmaf(bf2f(v0.x), w0, a0);
        a1 = fmaf(bf2f(v0.y), w0, a1);
        c0 = fmaf(bf2f(v1.x), w1, c0);
        c1 = fmaf(bf2f(v1.y), w1, c1);
    }
    // fallback for deg > 64 (statistically never for this graph, kept for safety)
    for (int k = 64 + half; k < d; k += 2) {
        int2 sw = csr[start + k];
        float w = __int_as_float(sw.y);
        const ushort2 v = *reinterpret_cast<const ushort2*>(
            &xMatB[(unsigned)sw.x * ROW_ELEMS + loff]);
        a0 = fmaf(bf2f(v.x), w, a0);
        a1 = fmaf(bf2f(v.y), w, a1);
    }
    a0 += c0; a1 += c1;
    a0 += __shfl_xor(a0, 32, 64);
    a1 += __shfl_xor(a1, 32, 64);
    a0 = fmaxf(a0, 0.f);
    a1 = fmaxf(a1, 0.f);
    if (half == 0) {
        ushort2 o; o.x = f2bf(a0); o.y = f2bf(a1);
        *reinterpret_cast<ushort2*>(
            &xMatOut[(size_t)n * ROW_ELEMS + (l + 1) * H_ + sl * 2]) = o;
    }
    float pr = halfReduceSum(a0 * mw[2 * sl] + a1 * mw[2 * sl + 1]);
    if (lane == 0) r[n * LP1 + (l + 1)] = pr + mb[0];
}

// one THREAD per node: stick-breaking t, entropy, gumbel-softmax weights tM
__global__ __launch_bounds__(256) void k_gate(
    const float* __restrict__ r, const float* __restrict__ gum,
    float* __restrict__ tM, float* __restrict__ entPart)
{
    __shared__ float lds[4];
    int tid = threadIdx.x;
    int n = blockIdx.x * 256 + tid;
    float ent = 0.f;
    if (n < N_NODES) {
        float t[LP1], lg[LP1];
        float cp = 1.f;
        #pragma unroll
        for (int j = 0; j < LP1; ++j) {
            float rv = r[n * LP1 + j];
            float s = 1.f / (1.f + expf(-rv));
            t[j] = (j == L_LAYERS) ? cp : s * cp;
            cp *= (1.f - s);
        }
        float mx = -INFINITY;
        #pragma unroll
        for (int j = 0; j < LP1; ++j) {
            float lt = logf(t[j] + EPS_T);
            ent -= t[j] * lt;
            lg[j] = lt + gum[n * LP1 + j];
            mx = fmaxf(mx, lg[j]);
        }
        float se = 0.f;
        #pragma unroll
        for (int j = 0; j < LP1; ++j) { lg[j] = expf(lg[j] - mx); se += lg[j]; }
        float inv = 1.f / se;
        #pragma unroll
        for (int j = 0; j < LP1; ++j) tM[n * LP1 + j] = lg[j] * inv;
    }
    float s = waveReduceSum(ent);
    int wave = tid >> 6, lane = tid & 63;
    if (lane == 0) lds[wave] = s;
    __syncthreads();
    if (tid == 0) entPart[blockIdx.x] = lds[0] + lds[1] + lds[2] + lds[3];
}

// per node (1 wave): mix xMat with tM, lin1, log_softmax
__global__ __launch_bounds__(256) void k_final(
    const u16* __restrict__ xMatB, const float* __restrict__ tM,
    const float* __restrict__ W1, const float* __restrict__ b1,
    float* __restrict__ out)
{
    __shared__ float mixLds[4][H_];
    int tid = threadIdx.x, wave = tid >> 6, lane = tid & 63;
    int n = blockIdx.x * 4 + wave;
    float tm = (lane < LP1) ? tM[n * LP1 + lane] : 0.f;
    float m = 0.f;
    #pragma unroll
    for (int j = 0; j < LP1; ++j) {
        float w = __shfl(tm, j, 64);
        m = fmaf(w, bf2f(xMatB[(size_t)n * ROW_ELEMS + j * H_ + lane]), m);
    }
    mixLds[wave][lane] = m;
    __syncthreads();
    float o = -INFINITY;
    if (lane < C_OUT) {
        float a = b1[lane];
        #pragma unroll 8
        for (int h = 0; h < H_; ++h)
            a = fmaf(mixLds[wave][h], W1[h * C_OUT + lane], a);
        o = a;
    }
    float omx = waveReduceMax(o);
    float ex = (lane < C_OUT) ? expf(o - omx) : 0.f;
    float es = waveReduceSum(ex);
    if (lane < C_OUT)
        out[(size_t)n * C_OUT + lane] = o - omx - logf(es);
}

__global__ __launch_bounds__(256) void k_entreduce(
    const float* __restrict__ part, int n, float scale, float* __restrict__ out)
{
    __shared__ float lds[4];
    int tid = threadIdx.x;
    float s = 0.f;
    for (int i = tid; i < n; i += 256) s += part[i];
    s = waveReduceSum(s);
    int wave = tid >> 6, lane = tid & 63;
    if (lane == 0) lds[wave] = s;
    __syncthreads();
    if (tid == 0) out[0] = (lds[0] + lds[1] + lds[2] + lds[3]) * scale;
}

extern "C" void kernel_launch(void* const* d_in, const int* in_sizes, int n_in,
                              void* d_out, int out_size, void* d_ws, size_t ws_size,
                              hipStream_t stream)
{
    const float* x   = (const float*)d_in[0];
    const float* ew  = (const float*)d_in[1];
    const float* gum = (const float*)d_in[2];
    const float* W0  = (const float*)d_in[3];
    const float* b0  = (const float*)d_in[4];
    const float* mw  = (const float*)d_in[5];
    const float* mb  = (const float*)d_in[6];
    const float* W1  = (const float*)d_in[7];
    const float* b1  = (const float*)d_in[8];
    const int* esrc  = (const int*)d_in[9];
    const int* edst  = (const int*)d_in[10];
    float* out = (float*)d_out;

    const size_t xMatBytes = (size_t)N_NODES * ROW_ELEMS * sizeof(u16); // 195,840,000
    const size_t rBytes    = (size_t)N_NODES * LP1 * sizeof(float);     //   6,120,000
    const size_t tMBytes   = (size_t)N_NODES * LP1 * sizeof(float);     //   6,120,000
    const size_t entBytes  = (size_t)(N_NODES / 4) * sizeof(float);
    const size_t degBytes  = (size_t)N_NODES * sizeof(int);
    const size_t curBytes  = (size_t)N_NODES * sizeof(int);
    const size_t rowBytes  = (size_t)N_NODES * sizeof(int);
    const size_t bsBytes   = 512;
    const size_t csrBytes  = (size_t)N_EDGES * sizeof(int2);            //  19,200,000
    const size_t need = xMatBytes + rBytes + tMBytes + entBytes + degBytes +
                        curBytes + rowBytes + bsBytes + csrBytes;       // ~229.6 MB
    if (ws_size < need) return;

    char* p = (char*)d_ws;
    u16*  xMatB    = (u16*)p;           p += xMatBytes;
    float* rbuf    = (float*)p;         p += rBytes;
    float* tMbuf   = (float*)p;         p += tMBytes;
    float* entP    = (float*)p;         p += entBytes;
    int*  deg      = (int*)p;           p += degBytes;
    int*  cursor   = (int*)p;           p += curBytes;   // deg+cursor zeroed together
    int*  rowstart = (int*)p;           p += rowBytes;
    int*  blockSums= (int*)p;           p += bsBytes;
    int2* csr      = (int2*)p;

    const int nodeBlocks = N_NODES / 4;                 // 42500 (exact)
    const int edgeBlocks = (N_EDGES + 255) / 256;       // 9375 (exact)
    const int gateBlocks = (N_NODES + 255) / 256;       // 665

    // CSR build  (k_zero4 tail spills into rowstart; scan rewrites it fully)
    k_zero4<<<333, 256, 0, stream>>>((float4*)deg);
    k_hist<<<edgeBlocks, 256, 0, stream>>>(edst, deg);
    k_scan1<<<SCAN_BLOCKS, SCAN_TPB, 0, stream>>>(deg, rowstart, blockSums);
    k_scan2<<<1, 64, 0, stream>>>(blockSums);
    k_scan3<<<SCAN_BLOCKS, SCAN_TPB, 0, stream>>>(rowstart, blockSums);
    k_bucket<<<edgeBlocks, 256, 0, stream>>>(esrc, edst, ew, rowstart, cursor, csr);

    // node pipeline
    k_lin0<<<2048, 256, 0, stream>>>(x, W0, b0, mw, mb, xMatB, rbuf);
    for (int l = 0; l < L_LAYERS; ++l)
        k_prop<<<nodeBlocks, 256, 0, stream>>>(xMatB, l, rowstart, deg, csr,
                                               mw, mb, xMatB, rbuf);
    k_gate<<<gateBlocks, 256, 0, stream>>>(rbuf, gum, tMbuf, entP);
    k_final<<<nodeBlocks, 256, 0, stream>>>(xMatB, tMbuf, W1, b1, out);
    k_entreduce<<<1, 256, 0, stream>>>(entP, gateBlocks, 1.0f / N_NODES,
                                       out + (size_t)N_NODES * C_OUT);
}

// Round 5
// 993.295 us; speedup vs baseline: 16.9094x; 1.1065x over previous
//
#include <hip/hip_runtime.h>
#include <hip/hip_bf16.h>

#define N_NODES 170000
#define N_EDGES 2400000
#define F_IN_   128
#define H_      64
#define C_OUT   40
#define L_LAYERS 8
#define LP1     9
#define EPS_T   1e-20f
#define ROW_ELEMS (LP1 * H_)   // 576 u16 per node row

typedef unsigned short u16;

__device__ __forceinline__ float bf2f(u16 u) {
    union { unsigned int i; float f; } c; c.i = ((unsigned int)u) << 16; return c.f;
}
__device__ __forceinline__ u16 f2bf(float f) {
    __hip_bfloat16 h = __float2bfloat16(f);           // RNE
    return *reinterpret_cast<u16*>(&h);
}

__device__ __forceinline__ float waveReduceSum(float v) {
    for (int m = 32; m; m >>= 1) v += __shfl_xor(v, m, 64);
    return v;
}
__device__ __forceinline__ float waveReduceMax(float v) {
    for (int m = 32; m; m >>= 1) v = fmaxf(v, __shfl_xor(v, m, 64));
    return v;
}

__global__ __launch_bounds__(256) void k_zero4(float4* __restrict__ p) {
    p[blockIdx.x * 256 + threadIdx.x] = make_float4(0.f, 0.f, 0.f, 0.f);
}

// ---------------- CSR build ----------------
__global__ __launch_bounds__(256) void k_hist(
    const int* __restrict__ edst, int* __restrict__ deg)
{
    int e = blockIdx.x * 256 + threadIdx.x;
    if (e < N_EDGES) atomicAdd(&deg[edst[e]], 1);
}

#define SCAN_TPB 256
#define SCAN_VPT 8
#define SCAN_EPB (SCAN_TPB * SCAN_VPT)   // 2048
#define SCAN_BLOCKS ((N_NODES + SCAN_EPB - 1) / SCAN_EPB)  // 84

__global__ __launch_bounds__(SCAN_TPB) void k_scan1(
    const int* __restrict__ deg, int* __restrict__ rowstart,
    int* __restrict__ blockSums)
{
    __shared__ int tsum[SCAN_TPB];
    int tid = threadIdx.x;
    int base = blockIdx.x * SCAN_EPB + tid * SCAN_VPT;
    int vals[SCAN_VPT];
    int local = 0;
    #pragma unroll
    for (int i = 0; i < SCAN_VPT; ++i) {
        int idx = base + i;
        int v = (idx < N_NODES) ? deg[idx] : 0;
        vals[i] = local;
        local += v;
    }
    tsum[tid] = local;
    __syncthreads();
    for (int off = 1; off < SCAN_TPB; off <<= 1) {
        int v = (tid >= off) ? tsum[tid - off] : 0;
        __syncthreads();
        tsum[tid] += v;
        __syncthreads();
    }
    int texcl = tsum[tid] - local;
    #pragma unroll
    for (int i = 0; i < SCAN_VPT; ++i) {
        int idx = base + i;
        if (idx < N_NODES) rowstart[idx] = texcl + vals[i];
    }
    if (tid == SCAN_TPB - 1) blockSums[blockIdx.x] = tsum[tid];
}

__global__ __launch_bounds__(64) void k_scan2(int* __restrict__ blockSums) {
    if (threadIdx.x == 0) {
        int acc = 0;
        for (int i = 0; i < SCAN_BLOCKS; ++i) {
            int v = blockSums[i];
            blockSums[i] = acc;
            acc += v;
        }
    }
}

__global__ __launch_bounds__(SCAN_TPB) void k_scan3(
    int* __restrict__ rowstart, const int* __restrict__ blockSums)
{
    int off = blockSums[blockIdx.x];
    int base = blockIdx.x * SCAN_EPB + threadIdx.x * SCAN_VPT;
    #pragma unroll
    for (int i = 0; i < SCAN_VPT; ++i) {
        int idx = base + i;
        if (idx < N_NODES) rowstart[idx] += off;
    }
}

__global__ __launch_bounds__(256) void k_bucket(
    const int* __restrict__ esrc, const int* __restrict__ edst,
    const float* __restrict__ ew, const int* __restrict__ rowstart,
    int* __restrict__ cursor, int2* __restrict__ csr)
{
    int e = blockIdx.x * 256 + threadIdx.x;
    if (e >= N_EDGES) return;
    int d = edst[e];
    int p = rowstart[d] + atomicAdd(&cursor[d], 1);
    csr[p] = make_int2(esrc[e], __float_as_int(ew[e]));
}

// ---------------- node pipeline ----------------
// Register-blocked lin0: block = 64 nodes, wave owns 16 nodes x 1 channel(=lane).
// W staged transposed+XOR-swizzled in LDS; read once per 4-k step (float4),
// amortized over 16 nodes -> 16x less W LDS traffic than one-node-per-wave.
#define L0_NPB 64
__global__ __launch_bounds__(256) void k_lin0(
    const float* __restrict__ x, const float* __restrict__ W0,
    const float* __restrict__ b0, const float* __restrict__ mw,
    const float* __restrict__ mb, u16* __restrict__ xMatB,
    float* __restrict__ r)
{
    __shared__ float Wt[H_ * F_IN_];        // 32 KB, Wt[c*128 + (k ^ ((c&7)<<2))]
    __shared__ float xr[L0_NPB * F_IN_];    // 32 KB
    int tid = threadIdx.x;
    for (int i = tid; i < F_IN_ * H_; i += 256) {
        int k = i >> 6, c = i & 63;
        Wt[c * F_IN_ + (k ^ ((c & 7) << 2))] = W0[i];
    }
    int nb = blockIdx.x * L0_NPB;
    const float4* x4 = (const float4*)(x + (size_t)nb * F_IN_);
    float4* xr4 = (float4*)xr;
    int nvalid = N_NODES - nb; if (nvalid > L0_NPB) nvalid = L0_NPB;
    int limit4 = nvalid * (F_IN_ / 4);
    for (int i = tid; i < L0_NPB * (F_IN_ / 4); i += 256)
        xr4[i] = (i < limit4) ? x4[i] : make_float4(0.f, 0.f, 0.f, 0.f);
    __syncthreads();

    int wave = tid >> 6, lane = tid & 63;
    const int mbase = wave * 16;
    float bias = b0[lane];
    float acc[16];
    #pragma unroll
    for (int j = 0; j < 16; ++j) acc[j] = bias;
    const int wrow = lane * F_IN_;
    const int wsw = (lane & 7) << 2;
    for (int k0 = 0; k0 < F_IN_; k0 += 4) {
        float4 wv = *(const float4*)&Wt[wrow + (k0 ^ wsw)];
        #pragma unroll
        for (int j = 0; j < 16; ++j) {
            float4 xv = *(const float4*)&xr[(mbase + j) * F_IN_ + k0];
            acc[j] = fmaf(xv.w, wv.w,
                     fmaf(xv.z, wv.z, fmaf(xv.y, wv.y, fmaf(xv.x, wv.x, acc[j]))));
        }
    }
    float mwv = mw[lane];
    for (int j = 0; j < 16; ++j) {
        int n = nb + mbase + j;
        if (n >= N_NODES) break;            // uniform per wave
        float v = fmaxf(acc[j], 0.f);
        xMatB[(size_t)n * ROW_ELEMS + lane] = f2bf(v);
        float pr = waveReduceSum(v * mwv);
        if (lane == 0) r[n * LP1] = pr + mb[0];
    }
}

// one wave per node; lanes = 16 channel-groups (ushort4) x 4 edge-quarters.
// Per 8 edges: 4 bpermute + 2 gather instrs (each gather touches 4 rows).
__global__ __launch_bounds__(256) void k_prop(
    const u16* __restrict__ xMatB, int l,
    const int* __restrict__ rowstart, const int* __restrict__ deg,
    const int2* __restrict__ csr,
    const float* __restrict__ mw, const float* __restrict__ mb,
    u16* __restrict__ xMatOut, float* __restrict__ r)
{
    int tid = threadIdx.x, wave = tid >> 6, lane = tid & 63;
    int n = blockIdx.x * 4 + wave;
    int sl = lane & 15, q = lane >> 4;
    int start = rowstart[n];
    int d = deg[n];

    int myS = 0; float myW = 0.f;          // lanes >= d: w=0 -> free masking
    if (lane < d) {
        int2 e = csr[start + lane];
        myS = e.x; myW = __int_as_float(e.y);
    }
    const unsigned loff = (unsigned)l * H_ + sl * 4;
    float a0 = 0.f, a1 = 0.f, a2 = 0.f, a3 = 0.f;
    float c0 = 0.f, c1 = 0.f, c2 = 0.f, c3 = 0.f;
    int dmax = (d < 64) ? d : 64;
    for (int kb = 0; kb < dmax; kb += 8) {   // 8 edges per iter: idx and idx+4
        int idx0 = kb + q;                   // <= 63 always
        int idx1 = kb + q + 4;               // <= 63 always
        int   s0 = __shfl(myS, idx0, 64);
        float w0 = __shfl(myW, idx0, 64);
        int   s1 = __shfl(myS, idx1, 64);
        float w1 = __shfl(myW, idx1, 64);
        ushort4 v0 = *reinterpret_cast<const ushort4*>(
            &xMatB[(size_t)(unsigned)s0 * ROW_ELEMS + loff]);
        ushort4 v1 = *reinterpret_cast<const ushort4*>(
            &xMatB[(size_t)(unsigned)s1 * ROW_ELEMS + loff]);
        a0 = fmaf(bf2f(v0.x), w0, a0);
        a1 = fmaf(bf2f(v0.y), w0, a1);
        a2 = fmaf(bf2f(v0.z), w0, a2);
        a3 = fmaf(bf2f(v0.w), w0, a3);
        c0 = fmaf(bf2f(v1.x), w1, c0);
        c1 = fmaf(bf2f(v1.y), w1, c1);
        c2 = fmaf(bf2f(v1.z), w1, c2);
        c3 = fmaf(bf2f(v1.w), w1, c3);
    }
    // fallback deg > 64 (statistically never here)
    for (int kb = 64; kb < d; kb += 4) {
        int idx = kb + q;
        if (idx < d) {
            int2 e = csr[start + idx];
            float w = __int_as_float(e.y);
            ushort4 v = *reinterpret_cast<const ushort4*>(
                &xMatB[(size_t)(unsigned)e.x * ROW_ELEMS + loff]);
            a0 = fmaf(bf2f(v.x), w, a0);
            a1 = fmaf(bf2f(v.y), w, a1);
            a2 = fmaf(bf2f(v.z), w, a2);
            a3 = fmaf(bf2f(v.w), w, a3);
        }
    }
    a0 += c0; a1 += c1; a2 += c2; a3 += c3;
    // reduce across the 4 quarters
    a0 += __shfl_xor(a0, 16, 64); a0 += __shfl_xor(a0, 32, 64);
    a1 += __shfl_xor(a1, 16, 64); a1 += __shfl_xor(a1, 32, 64);
    a2 += __shfl_xor(a2, 16, 64); a2 += __shfl_xor(a2, 32, 64);
    a3 += __shfl_xor(a3, 16, 64); a3 += __shfl_xor(a3, 32, 64);
    a0 = fmaxf(a0, 0.f); a1 = fmaxf(a1, 0.f);
    a2 = fmaxf(a2, 0.f); a3 = fmaxf(a3, 0.f);
    if (q == 0) {
        ushort4 o; o.x = f2bf(a0); o.y = f2bf(a1); o.z = f2bf(a2); o.w = f2bf(a3);
        *reinterpret_cast<ushort4*>(
            &xMatOut[(size_t)n * ROW_ELEMS + (l + 1) * H_ + sl * 4]) = o;
    }
    float dot = a0 * mw[4 * sl] + a1 * mw[4 * sl + 1] +
                a2 * mw[4 * sl + 2] + a3 * mw[4 * sl + 3];
    float pr = waveReduceSum(dot) * 0.25f;   // all 4 quarters hold identical sums
    if (lane == 0) r[n * LP1 + (l + 1)] = pr + mb[0];
}

// one THREAD per node: stick-breaking t, entropy, gumbel-softmax weights tM
__global__ __launch_bounds__(256) void k_gate(
    const float* __restrict__ r, const float* __restrict__ gum,
    float* __restrict__ tM, float* __restrict__ entPart)
{
    __shared__ float lds[4];
    int tid = threadIdx.x;
    int n = blockIdx.x * 256 + tid;
    float ent = 0.f;
    if (n < N_NODES) {
        float t[LP1], lg[LP1];
        float cp = 1.f;
        #pragma unroll
        for (int j = 0; j < LP1; ++j) {
            float rv = r[n * LP1 + j];
            float s = 1.f / (1.f + expf(-rv));
            t[j] = (j == L_LAYERS) ? cp : s * cp;
            cp *= (1.f - s);
        }
        float mx = -INFINITY;
        #pragma unroll
        for (int j = 0; j < LP1; ++j) {
            float lt = logf(t[j] + EPS_T);
            ent -= t[j] * lt;
            lg[j] = lt + gum[n * LP1 + j];
            mx = fmaxf(mx, lg[j]);
        }
        float se = 0.f;
        #pragma unroll
        for (int j = 0; j < LP1; ++j) { lg[j] = expf(lg[j] - mx); se += lg[j]; }
        float inv = 1.f / se;
        #pragma unroll
        for (int j = 0; j < LP1; ++j) tM[n * LP1 + j] = lg[j] * inv;
    }
    float s = waveReduceSum(ent);
    int wave = tid >> 6, lane = tid & 63;
    if (lane == 0) lds[wave] = s;
    __syncthreads();
    if (tid == 0) entPart[blockIdx.x] = lds[0] + lds[1] + lds[2] + lds[3];
}

// per node (1 wave): mix xMat with tM, lin1, log_softmax
__global__ __launch_bounds__(256) void k_final(
    const u16* __restrict__ xMatB, const float* __restrict__ tM,
    const float* __restrict__ W1, const float* __restrict__ b1,
    float* __restrict__ out)
{
    __shared__ float mixLds[4][H_];
    int tid = threadIdx.x, wave = tid >> 6, lane = tid & 63;
    int n = blockIdx.x * 4 + wave;
    float tm = (lane < LP1) ? tM[n * LP1 + lane] : 0.f;
    float m = 0.f;
    #pragma unroll
    for (int j = 0; j < LP1; ++j) {
        float w = __shfl(tm, j, 64);
        m = fmaf(w, bf2f(xMatB[(size_t)n * ROW_ELEMS + j * H_ + lane]), m);
    }
    mixLds[wave][lane] = m;
    __syncthreads();
    float o = -INFINITY;
    if (lane < C_OUT) {
        float a = b1[lane];
        #pragma unroll 8
        for (int h = 0; h < H_; ++h)
            a = fmaf(mixLds[wave][h], W1[h * C_OUT + lane], a);
        o = a;
    }
    float omx = waveReduceMax(o);
    float ex = (lane < C_OUT) ? expf(o - omx) : 0.f;
    float es = waveReduceSum(ex);
    if (lane < C_OUT)
        out[(size_t)n * C_OUT + lane] = o - omx - logf(es);
}

__global__ __launch_bounds__(256) void k_entreduce(
    const float* __restrict__ part, int n, float scale, float* __restrict__ out)
{
    __shared__ float lds[4];
    int tid = threadIdx.x;
    float s = 0.f;
    for (int i = tid; i < n; i += 256) s += part[i];
    s = waveReduceSum(s);
    int wave = tid >> 6, lane = tid & 63;
    if (lane == 0) lds[wave] = s;
    __syncthreads();
    if (tid == 0) out[0] = (lds[0] + lds[1] + lds[2] + lds[3]) * scale;
}

extern "C" void kernel_launch(void* const* d_in, const int* in_sizes, int n_in,
                              void* d_out, int out_size, void* d_ws, size_t ws_size,
                              hipStream_t stream)
{
    const float* x   = (const float*)d_in[0];
    const float* ew  = (const float*)d_in[1];
    const float* gum = (const float*)d_in[2];
    const float* W0  = (const float*)d_in[3];
    const float* b0  = (const float*)d_in[4];
    const float* mw  = (const float*)d_in[5];
    const float* mb  = (const float*)d_in[6];
    const float* W1  = (const float*)d_in[7];
    const float* b1  = (const float*)d_in[8];
    const int* esrc  = (const int*)d_in[9];
    const int* edst  = (const int*)d_in[10];
    float* out = (float*)d_out;

    const size_t xMatBytes = (size_t)N_NODES * ROW_ELEMS * sizeof(u16); // 195,840,000
    const size_t rBytes    = (size_t)N_NODES * LP1 * sizeof(float);
    const size_t tMBytes   = (size_t)N_NODES * LP1 * sizeof(float);
    const size_t entBytes  = (size_t)((N_NODES + 255) / 256) * sizeof(float);
    const size_t degBytes  = (size_t)N_NODES * sizeof(int);
    const size_t curBytes  = (size_t)N_NODES * sizeof(int);
    const size_t rowBytes  = (size_t)N_NODES * sizeof(int);
    const size_t bsBytes   = 512;
    const size_t csrBytes  = (size_t)N_EDGES * sizeof(int2);            //  19,200,000
    const size_t need = xMatBytes + rBytes + tMBytes + entBytes + degBytes +
                        curBytes + rowBytes + bsBytes + csrBytes;       // ~229.6 MB
    if (ws_size < need) return;

    char* p = (char*)d_ws;
    u16*  xMatB    = (u16*)p;           p += xMatBytes;
    float* rbuf    = (float*)p;         p += rBytes;
    float* tMbuf   = (float*)p;         p += tMBytes;
    float* entP    = (float*)p;         p += entBytes;
    int*  deg      = (int*)p;           p += degBytes;
    int*  cursor   = (int*)p;           p += curBytes;   // deg+cursor zeroed together
    int*  rowstart = (int*)p;           p += rowBytes;
    int*  blockSums= (int*)p;           p += bsBytes;
    int2* csr      = (int2*)p;

    const int nodeBlocks = N_NODES / 4;                 // 42500 (exact)
    const int edgeBlocks = (N_EDGES + 255) / 256;       // 9375 (exact)
    const int gateBlocks = (N_NODES + 255) / 256;       // 665
    const int lin0Blocks = (N_NODES + L0_NPB - 1) / L0_NPB; // 2657

    // CSR build  (k_zero4 tail spills into rowstart; scan rewrites it fully)
    k_zero4<<<333, 256, 0, stream>>>((float4*)deg);
    k_hist<<<edgeBlocks, 256, 0, stream>>>(edst, deg);
    k_scan1<<<SCAN_BLOCKS, SCAN_TPB, 0, stream>>>(deg, rowstart, blockSums);
    k_scan2<<<1, 64, 0, stream>>>(blockSums);
    k_scan3<<<SCAN_BLOCKS, SCAN_TPB, 0, stream>>>(rowstart, blockSums);
    k_bucket<<<edgeBlocks, 256, 0, stream>>>(esrc, edst, ew, rowstart, cursor, csr);

    // node pipeline
    k_lin0<<<lin0Blocks, 256, 0, stream>>>(x, W0, b0, mw, mb, xMatB, rbuf);
    for (int l = 0; l < L_LAYERS; ++l)
        k_prop<<<nodeBlocks, 256, 0, stream>>>(xMatB, l, rowstart, deg, csr,
                                               mw, mb, xMatB, rbuf);
    k_gate<<<gateBlocks, 256, 0, stream>>>(rbuf, gum, tMbuf, entP);
    k_final<<<nodeBlocks, 256, 0, stream>>>(xMatB, tMbuf, W1, b1, out);
    k_entreduce<<<1, 256, 0, stream>>>(entP, gateBlocks, 1.0f / N_NODES,
                                       out + (size_t)N_NODES * C_OUT);
}

// Round 8
// 958.341 us; speedup vs baseline: 17.5262x; 1.0365x over previous
//
#include <hip/hip_runtime.h>
#include <hip/hip_bf16.h>

#define N_NODES 170000
#define N_EDGES 2400000
#define F_IN_   128
#define H_      64
#define C_OUT   40
#define L_LAYERS 8
#define LP1     9
#define EPS_T   1e-20f
#define ROW_ELEMS (LP1 * H_)   // 576 u16 per node row

typedef unsigned short u16;

__device__ __forceinline__ float bf2f(u16 u) {
    union { unsigned int i; float f; } c; c.i = ((unsigned int)u) << 16; return c.f;
}
__device__ __forceinline__ u16 f2bf(float f) {
    __hip_bfloat16 h = __float2bfloat16(f);           // RNE
    return *reinterpret_cast<u16*>(&h);
}

__device__ __forceinline__ float waveReduceSum(float v) {
    for (int m = 32; m; m >>= 1) v += __shfl_xor(v, m, 64);
    return v;
}
__device__ __forceinline__ float waveReduceMax(float v) {
    for (int m = 32; m; m >>= 1) v = fmaxf(v, __shfl_xor(v, m, 64));
    return v;
}

__global__ __launch_bounds__(256) void k_zero4(float4* __restrict__ p) {
    p[blockIdx.x * 256 + threadIdx.x] = make_float4(0.f, 0.f, 0.f, 0.f);
}

// ---------------- CSR build ----------------
__global__ __launch_bounds__(256) void k_hist(
    const int* __restrict__ edst, int* __restrict__ deg)
{
    int e = blockIdx.x * 256 + threadIdx.x;
    if (e < N_EDGES) atomicAdd(&deg[edst[e]], 1);
}

#define SCAN_TPB 256
#define SCAN_VPT 8
#define SCAN_EPB (SCAN_TPB * SCAN_VPT)   // 2048
#define SCAN_BLOCKS ((N_NODES + SCAN_EPB - 1) / SCAN_EPB)  // 84

__global__ __launch_bounds__(SCAN_TPB) void k_scan1(
    const int* __restrict__ deg, int* __restrict__ rowstart,
    int* __restrict__ blockSums)
{
    __shared__ int tsum[SCAN_TPB];
    int tid = threadIdx.x;
    int base = blockIdx.x * SCAN_EPB + tid * SCAN_VPT;
    int vals[SCAN_VPT];
    int local = 0;
    #pragma unroll
    for (int i = 0; i < SCAN_VPT; ++i) {
        int idx = base + i;
        int v = (idx < N_NODES) ? deg[idx] : 0;
        vals[i] = local;
        local += v;
    }
    tsum[tid] = local;
    __syncthreads();
    for (int off = 1; off < SCAN_TPB; off <<= 1) {
        int v = (tid >= off) ? tsum[tid - off] : 0;
        __syncthreads();
        tsum[tid] += v;
        __syncthreads();
    }
    int texcl = tsum[tid] - local;
    #pragma unroll
    for (int i = 0; i < SCAN_VPT; ++i) {
        int idx = base + i;
        if (idx < N_NODES) rowstart[idx] = texcl + vals[i];
    }
    if (tid == SCAN_TPB - 1) blockSums[blockIdx.x] = tsum[tid];
}

__global__ __launch_bounds__(64) void k_scan2(int* __restrict__ blockSums) {
    if (threadIdx.x == 0) {
        int acc = 0;
        for (int i = 0; i < SCAN_BLOCKS; ++i) {
            int v = blockSums[i];
            blockSums[i] = acc;
            acc += v;
        }
    }
}

__global__ __launch_bounds__(SCAN_TPB) void k_scan3(
    int* __restrict__ rowstart, const int* __restrict__ blockSums)
{
    int off = blockSums[blockIdx.x];
    int base = blockIdx.x * SCAN_EPB + threadIdx.x * SCAN_VPT;
    #pragma unroll
    for (int i = 0; i < SCAN_VPT; ++i) {
        int idx = base + i;
        if (idx < N_NODES) rowstart[idx] += off;
    }
}

// dst-range pass: writes confined to a ~2.4 MB CSR window -> L2 write-combining
__global__ __launch_bounds__(256) void k_bucket(
    const int* __restrict__ esrc, const int* __restrict__ edst,
    const float* __restrict__ ew, const int* __restrict__ rowstart,
    int* __restrict__ cursor, int2* __restrict__ csr, int lo, int hi)
{
    int e = blockIdx.x * 256 + threadIdx.x;
    if (e >= N_EDGES) return;
    int d = edst[e];
    if (d < lo || d >= hi) return;
    int p = rowstart[d] + atomicAdd(&cursor[d], 1);
    csr[p] = make_int2(esrc[e], __float_as_int(ew[e]));
}

// ---------------- node pipeline ----------------
// Register-blocked lin0: block = 64 nodes, wave owns 16 nodes x 1 channel(=lane).
#define L0_NPB 64
__global__ __launch_bounds__(256) void k_lin0(
    const float* __restrict__ x, const float* __restrict__ W0,
    const float* __restrict__ b0, const float* __restrict__ mw,
    const float* __restrict__ mb, u16* __restrict__ xMatB,
    float* __restrict__ r)
{
    __shared__ float Wt[H_ * F_IN_];        // 32 KB, Wt[c*128 + (k ^ ((c&7)<<2))]
    __shared__ float xr[L0_NPB * F_IN_];    // 32 KB
    int tid = threadIdx.x;
    for (int i = tid; i < F_IN_ * H_; i += 256) {
        int k = i >> 6, c = i & 63;
        Wt[c * F_IN_ + (k ^ ((c & 7) << 2))] = W0[i];
    }
    int nb = blockIdx.x * L0_NPB;
    const float4* x4 = (const float4*)(x + (size_t)nb * F_IN_);
    float4* xr4 = (float4*)xr;
    int nvalid = N_NODES - nb; if (nvalid > L0_NPB) nvalid = L0_NPB;
    int limit4 = nvalid * (F_IN_ / 4);
    for (int i = tid; i < L0_NPB * (F_IN_ / 4); i += 256)
        xr4[i] = (i < limit4) ? x4[i] : make_float4(0.f, 0.f, 0.f, 0.f);
    __syncthreads();

    int wave = tid >> 6, lane = tid & 63;
    const int mbase = wave * 16;
    float bias = b0[lane];
    float acc[16];
    #pragma unroll
    for (int j = 0; j < 16; ++j) acc[j] = bias;
    const int wrow = lane * F_IN_;
    const int wsw = (lane & 7) << 2;
    for (int k0 = 0; k0 < F_IN_; k0 += 4) {
        float4 wv = *(const float4*)&Wt[wrow + (k0 ^ wsw)];
        #pragma unroll
        for (int j = 0; j < 16; ++j) {
            float4 xv = *(const float4*)&xr[(mbase + j) * F_IN_ + k0];
            acc[j] = fmaf(xv.w, wv.w,
                     fmaf(xv.z, wv.z, fmaf(xv.y, wv.y, fmaf(xv.x, wv.x, acc[j]))));
        }
    }
    float mwv = mw[lane];
    for (int j = 0; j < 16; ++j) {
        int n = nb + mbase + j;
        if (n >= N_NODES) break;            // uniform per wave
        float v = fmaxf(acc[j], 0.f);
        xMatB[(size_t)n * ROW_ELEMS + lane] = f2bf(v);
        float pr = waveReduceSum(v * mwv);
        if (lane == 0) r[n * LP1] = pr + mb[0];
    }
}

// one wave per node; lanes = 16 channel-quads (ushort4) x 4 edge-quarters.
// 16 edges per iteration via 4 independent gather chains; tail slots clamp
// their broadcast index to deg-1 (weight masked to 0) so the wasted gather
// merges with a useful row's transaction.
__global__ __launch_bounds__(256) void k_prop(
    const u16* __restrict__ xMatB, int l,
    const int* __restrict__ rowstart, const int* __restrict__ deg,
    const int2* __restrict__ csr,
    const float* __restrict__ mw, const float* __restrict__ mb,
    u16* __restrict__ xMatOut, float* __restrict__ r)
{
    int tid = threadIdx.x, wave = tid >> 6, lane = tid & 63;
    int n = blockIdx.x * 4 + wave;
    int sl = lane & 15, q = lane >> 4;
    int start = rowstart[n];
    int d = deg[n];
    int dm1 = (d > 0) ? (d - 1) : 0;

    int myS = 0; float myW = 0.f;
    if (lane < d) {
        int2 e = csr[start + lane];
        myS = e.x; myW = __int_as_float(e.y);
    }
    const unsigned loff = (unsigned)l * H_ + sl * 4;

    float a0x = 0.f, a0y = 0.f, a0z = 0.f, a0w = 0.f;
    float a1x = 0.f, a1y = 0.f, a1z = 0.f, a1w = 0.f;
    float a2x = 0.f, a2y = 0.f, a2z = 0.f, a2w = 0.f;
    float a3x = 0.f, a3y = 0.f, a3z = 0.f, a3w = 0.f;

    int dmax = (d < 64) ? d : 64;
    int kb = 0;
    do {
        int idx0 = kb + q;
        int idx1 = kb + q + 4;
        int idx2 = kb + q + 8;
        int idx3 = kb + q + 12;
        int ic0 = (idx0 < dm1) ? idx0 : dm1;
        int ic1 = (idx1 < dm1) ? idx1 : dm1;
        int ic2 = (idx2 < dm1) ? idx2 : dm1;
        int ic3 = (idx3 < dm1) ? idx3 : dm1;
        int   s0 = __shfl(myS, ic0, 64); float w0 = __shfl(myW, ic0, 64);
        int   s1 = __shfl(myS, ic1, 64); float w1 = __shfl(myW, ic1, 64);
        int   s2 = __shfl(myS, ic2, 64); float w2 = __shfl(myW, ic2, 64);
        int   s3 = __shfl(myS, ic3, 64); float w3 = __shfl(myW, ic3, 64);
        if (idx0 >= d) w0 = 0.f;
        if (idx1 >= d) w1 = 0.f;
        if (idx2 >= d) w2 = 0.f;
        if (idx3 >= d) w3 = 0.f;
        ushort4 v0 = *reinterpret_cast<const ushort4*>(
            &xMatB[(size_t)(unsigned)s0 * ROW_ELEMS + loff]);
        ushort4 v1 = *reinterpret_cast<const ushort4*>(
            &xMatB[(size_t)(unsigned)s1 * ROW_ELEMS + loff]);
        ushort4 v2 = *reinterpret_cast<const ushort4*>(
            &xMatB[(size_t)(unsigned)s2 * ROW_ELEMS + loff]);
        ushort4 v3 = *reinterpret_cast<const ushort4*>(
            &xMatB[(size_t)(unsigned)s3 * ROW_ELEMS + loff]);
        a0x = fmaf(bf2f(v0.x), w0, a0x); a0y = fmaf(bf2f(v0.y), w0, a0y);
        a0z = fmaf(bf2f(v0.z), w0, a0z); a0w = fmaf(bf2f(v0.w), w0, a0w);
        a1x = fmaf(bf2f(v1.x), w1, a1x); a1y = fmaf(bf2f(v1.y), w1, a1y);
        a1z = fmaf(bf2f(v1.z), w1, a1z); a1w = fmaf(bf2f(v1.w), w1, a1w);
        a2x = fmaf(bf2f(v2.x), w2, a2x); a2y = fmaf(bf2f(v2.y), w2, a2y);
        a2z = fmaf(bf2f(v2.z), w2, a2z); a2w = fmaf(bf2f(v2.w), w2, a2w);
        a3x = fmaf(bf2f(v3.x), w3, a3x); a3y = fmaf(bf2f(v3.y), w3, a3y);
        a3z = fmaf(bf2f(v3.z), w3, a3z); a3w = fmaf(bf2f(v3.w), w3, a3w);
        kb += 16;
    } while (kb < dmax);

    // fallback deg > 64 (statistically never for Poisson(14.1))
    for (int kb2 = 64; kb2 < d; kb2 += 16) {
        #pragma unroll
        for (int j = 0; j < 4; ++j) {
            int idx = kb2 + j * 4 + q;
            if (idx < d) {
                int2 e = csr[start + idx];
                float w = __int_as_float(e.y);
                ushort4 v = *reinterpret_cast<const ushort4*>(
                    &xMatB[(size_t)(unsigned)e.x * ROW_ELEMS + loff]);
                a0x = fmaf(bf2f(v.x), w, a0x);
                a0y = fmaf(bf2f(v.y), w, a0y);
                a0z = fmaf(bf2f(v.z), w, a0z);
                a0w = fmaf(bf2f(v.w), w, a0w);
            }
        }
    }

    float r0 = a0x + a1x + a2x + a3x;
    float r1 = a0y + a1y + a2y + a3y;
    float r2 = a0z + a1z + a2z + a3z;
    float r3 = a0w + a1w + a2w + a3w;
    // reduce across the 4 quarters
    r0 += __shfl_xor(r0, 16, 64); r0 += __shfl_xor(r0, 32, 64);
    r1 += __shfl_xor(r1, 16, 64); r1 += __shfl_xor(r1, 32, 64);
    r2 += __shfl_xor(r2, 16, 64); r2 += __shfl_xor(r2, 32, 64);
    r3 += __shfl_xor(r3, 16, 64); r3 += __shfl_xor(r3, 32, 64);
    r0 = fmaxf(r0, 0.f); r1 = fmaxf(r1, 0.f);
    r2 = fmaxf(r2, 0.f); r3 = fmaxf(r3, 0.f);
    if (q == 0) {
        ushort4 o; o.x = f2bf(r0); o.y = f2bf(r1); o.z = f2bf(r2); o.w = f2bf(r3);
        *reinterpret_cast<ushort4*>(
            &xMatOut[(size_t)n * ROW_ELEMS + (l + 1) * H_ + sl * 4]) = o;
    }
    // quarters hold identical values -> 16-lane reduce gives the full dot
    float dot = r0 * mw[4 * sl] + r1 * mw[4 * sl + 1] +
                r2 * mw[4 * sl + 2] + r3 * mw[4 * sl + 3];
    dot += __shfl_xor(dot, 1, 64);
    dot += __shfl_xor(dot, 2, 64);
    dot += __shfl_xor(dot, 4, 64);
    dot += __shfl_xor(dot, 8, 64);
    if (lane == 0) r[n * LP1 + (l + 1)] = dot + mb[0];
}

// one THREAD per node: stick-breaking t, entropy, gumbel-softmax weights tM
__global__ __launch_bounds__(256) void k_gate(
    const float* __restrict__ r, const float* __restrict__ gum,
    float* __restrict__ tM, float* __restrict__ entPart)
{
    __shared__ float lds[4];
    int tid = threadIdx.x;
    int n = blockIdx.x * 256 + tid;
    float ent = 0.f;
    if (n < N_NODES) {
        float t[LP1], lg[LP1];
        float cp = 1.f;
        #pragma unroll
        for (int j = 0; j < LP1; ++j) {
            float rv = r[n * LP1 + j];
            float s = 1.f / (1.f + expf(-rv));
            t[j] = (j == L_LAYERS) ? cp : s * cp;
            cp *= (1.f - s);
        }
        float mx = -INFINITY;
        #pragma unroll
        for (int j = 0; j < LP1; ++j) {
            float lt = logf(t[j] + EPS_T);
            ent -= t[j] * lt;
            lg[j] = lt + gum[n * LP1 + j];
            mx = fmaxf(mx, lg[j]);
        }
        float se = 0.f;
        #pragma unroll
        for (int j = 0; j < LP1; ++j) { lg[j] = expf(lg[j] - mx); se += lg[j]; }
        float inv = 1.f / se;
        #pragma unroll
        for (int j = 0; j < LP1; ++j) tM[n * LP1 + j] = lg[j] * inv;
    }
    float s = waveReduceSum(ent);
    int wave = tid >> 6, lane = tid & 63;
    if (lane == 0) lds[wave] = s;
    __syncthreads();
    if (tid == 0) entPart[blockIdx.x] = lds[0] + lds[1] + lds[2] + lds[3];
}

// per node (1 wave): mix xMat with tM, lin1, log_softmax
__global__ __launch_bounds__(256) void k_final(
    const u16* __restrict__ xMatB, const float* __restrict__ tM,
    const float* __restrict__ W1, const float* __restrict__ b1,
    float* __restrict__ out)
{
    __shared__ float mixLds[4][H_];
    int tid = threadIdx.x, wave = tid >> 6, lane = tid & 63;
    int n = blockIdx.x * 4 + wave;
    float tm = (lane < LP1) ? tM[n * LP1 + lane] : 0.f;
    float m = 0.f;
    #pragma unroll
    for (int j = 0; j < LP1; ++j) {
        float w = __shfl(tm, j, 64);
        m = fmaf(w, bf2f(xMatB[(size_t)n * ROW_ELEMS + j * H_ + lane]), m);
    }
    mixLds[wave][lane] = m;
    __syncthreads();
    float o = -INFINITY;
    if (lane < C_OUT) {
        float a = b1[lane];
        #pragma unroll 8
        for (int h = 0; h < H_; ++h)
            a = fmaf(mixLds[wave][h], W1[h * C_OUT + lane], a);
        o = a;
    }
    float omx = waveReduceMax(o);
    float ex = (lane < C_OUT) ? expf(o - omx) : 0.f;
    float es = waveReduceSum(ex);
    if (lane < C_OUT)
        out[(size_t)n * C_OUT + lane] = o - omx - logf(es);
}

__global__ __launch_bounds__(256) void k_entreduce(
    const float* __restrict__ part, int n, float scale, float* __restrict__ out)
{
    __shared__ float lds[4];
    int tid = threadIdx.x;
    float s = 0.f;
    for (int i = tid; i < n; i += 256) s += part[i];
    s = waveReduceSum(s);
    int wave = tid >> 6, lane = tid & 63;
    if (lane == 0) lds[wave] = s;
    __syncthreads();
    if (tid == 0) out[0] = (lds[0] + lds[1] + lds[2] + lds[3]) * scale;
}

extern "C" void kernel_launch(void* const* d_in, const int* in_sizes, int n_in,
                              void* d_out, int out_size, void* d_ws, size_t ws_size,
                              hipStream_t stream)
{
    const float* x   = (const float*)d_in[0];
    const float* ew  = (const float*)d_in[1];
    const float* gum = (const float*)d_in[2];
    const float* W0  = (const float*)d_in[3];
    const float* b0  = (const float*)d_in[4];
    const float* mw  = (const float*)d_in[5];
    const float* mb  = (const float*)d_in[6];
    const float* W1  = (const float*)d_in[7];
    const float* b1  = (const float*)d_in[8];
    const int* esrc  = (const int*)d_in[9];
    const int* edst  = (const int*)d_in[10];
    float* out = (float*)d_out;

    const size_t xMatBytes = (size_t)N_NODES * ROW_ELEMS * sizeof(u16); // 195,840,000
    const size_t rBytes    = (size_t)N_NODES * LP1 * sizeof(float);
    const size_t tMBytes   = (size_t)N_NODES * LP1 * sizeof(float);
    const size_t entBytes  = (size_t)((N_NODES + 255) / 256) * sizeof(float);
    const size_t degBytes  = (size_t)N_NODES * sizeof(int);
    const size_t curBytes  = (size_t)N_NODES * sizeof(int);
    const size_t rowBytes  = (size_t)N_NODES * sizeof(int);
    const size_t bsBytes   = 512;
    const size_t csrBytes  = (size_t)N_EDGES * sizeof(int2);            //  19,200,000
    const size_t need = xMatBytes + rBytes + tMBytes + entBytes + degBytes +
                        curBytes + rowBytes + bsBytes + csrBytes;       // ~229.6 MB
    if (ws_size < need) return;

    char* p = (char*)d_ws;
    u16*  xMatB    = (u16*)p;           p += xMatBytes;
    float* rbuf    = (float*)p;         p += rBytes;
    float* tMbuf   = (float*)p;         p += tMBytes;
    float* entP    = (float*)p;         p += entBytes;
    int*  deg      = (int*)p;           p += degBytes;
    int*  cursor   = (int*)p;           p += curBytes;   // deg+cursor zeroed together
    int*  rowstart = (int*)p;           p += rowBytes;
    int*  blockSums= (int*)p;           p += bsBytes;
    int2* csr      = (int2*)p;

    const int nodeBlocks = N_NODES / 4;                 // 42500 (exact)
    const int edgeBlocks = (N_EDGES + 255) / 256;       // 9375 (exact)
    const int gateBlocks = (N_NODES + 255) / 256;       // 665
    const int lin0Blocks = (N_NODES + L0_NPB - 1) / L0_NPB; // 2657

    // CSR build  (k_zero4 tail spills into rowstart; scan rewrites it fully)
    k_zero4<<<333, 256, 0, stream>>>((float4*)deg);
    k_hist<<<edgeBlocks, 256, 0, stream>>>(edst, deg);
    k_scan1<<<SCAN_BLOCKS, SCAN_TPB, 0, stream>>>(deg, rowstart, blockSums);
    k_scan2<<<1, 64, 0, stream>>>(blockSums);
    k_scan3<<<SCAN_BLOCKS, SCAN_TPB, 0, stream>>>(rowstart, blockSums);
    const int STEP = N_NODES / 8;                       // 21250
    for (int i = 0; i < 8; ++i)
        k_bucket<<<edgeBlocks, 256, 0, stream>>>(esrc, edst, ew, rowstart,
                                                 cursor, csr, i * STEP,
                                                 (i + 1) * STEP);

    // node pipeline
    k_lin0<<<lin0Blocks, 256, 0, stream>>>(x, W0, b0, mw, mb, xMatB, rbuf);
    for (int l = 0; l < L_LAYERS; ++l)
        k_prop<<<nodeBlocks, 256, 0, stream>>>(xMatB, l, rowstart, deg, csr,
                                               mw, mb, xMatB, rbuf);
    k_gate<<<gateBlocks, 256, 0, stream>>>(rbuf, gum, tMbuf, entP);
    k_final<<<nodeBlocks, 256, 0, stream>>>(xMatB, tMbuf, W1, b1, out);
    k_entreduce<<<1, 256, 0, stream>>>(entP, gateBlocks, 1.0f / N_NODES,
                                       out + (size_t)N_NODES * C_OUT);
}

// Round 9
// 872.861 us; speedup vs baseline: 19.2425x; 1.0979x over previous
//
#include <hip/hip_runtime.h>
#include <hip/hip_bf16.h>

#define N_NODES 170000
#define N_EDGES 2400000
#define F_IN_   128
#define H_      64
#define C_OUT   40
#define L_LAYERS 8
#define LP1     9
#define EPS_T   1e-20f
#define ROW_ELEMS (LP1 * H_)   // 576 u16 per node row

typedef unsigned short u16;
typedef short bf16x8 __attribute__((ext_vector_type(8)));
typedef float f32x4 __attribute__((ext_vector_type(4)));

__device__ __forceinline__ float bf2f(u16 u) {
    union { unsigned int i; float f; } c; c.i = ((unsigned int)u) << 16; return c.f;
}
__device__ __forceinline__ u16 f2bf(float f) {
    __hip_bfloat16 h = __float2bfloat16(f);           // RNE
    return *reinterpret_cast<u16*>(&h);
}

__device__ __forceinline__ float waveReduceSum(float v) {
    for (int m = 32; m; m >>= 1) v += __shfl_xor(v, m, 64);
    return v;
}
__device__ __forceinline__ float waveReduceMax(float v) {
    for (int m = 32; m; m >>= 1) v = fmaxf(v, __shfl_xor(v, m, 64));
    return v;
}

__global__ __launch_bounds__(256) void k_zero4(float4* __restrict__ p) {
    p[blockIdx.x * 256 + threadIdx.x] = make_float4(0.f, 0.f, 0.f, 0.f);
}

// ---------------- CSR build ----------------
__global__ __launch_bounds__(256) void k_hist(
    const int* __restrict__ edst, int* __restrict__ deg)
{
    int e = blockIdx.x * 256 + threadIdx.x;
    if (e < N_EDGES) atomicAdd(&deg[edst[e]], 1);
}

#define SCAN_TPB 256
#define SCAN_VPT 8
#define SCAN_EPB (SCAN_TPB * SCAN_VPT)   // 2048
#define SCAN_BLOCKS ((N_NODES + SCAN_EPB - 1) / SCAN_EPB)  // 84

__global__ __launch_bounds__(SCAN_TPB) void k_scan1(
    const int* __restrict__ deg, int* __restrict__ rowstart,
    int* __restrict__ blockSums)
{
    __shared__ int tsum[SCAN_TPB];
    int tid = threadIdx.x;
    int base = blockIdx.x * SCAN_EPB + tid * SCAN_VPT;
    int vals[SCAN_VPT];
    int local = 0;
    #pragma unroll
    for (int i = 0; i < SCAN_VPT; ++i) {
        int idx = base + i;
        int v = (idx < N_NODES) ? deg[idx] : 0;
        vals[i] = local;
        local += v;
    }
    tsum[tid] = local;
    __syncthreads();
    for (int off = 1; off < SCAN_TPB; off <<= 1) {
        int v = (tid >= off) ? tsum[tid - off] : 0;
        __syncthreads();
        tsum[tid] += v;
        __syncthreads();
    }
    int texcl = tsum[tid] - local;
    #pragma unroll
    for (int i = 0; i < SCAN_VPT; ++i) {
        int idx = base + i;
        if (idx < N_NODES) rowstart[idx] = texcl + vals[i];
    }
    if (tid == SCAN_TPB - 1) blockSums[blockIdx.x] = tsum[tid];
}

__global__ __launch_bounds__(64) void k_scan2(int* __restrict__ blockSums) {
    if (threadIdx.x == 0) {
        int acc = 0;
        for (int i = 0; i < SCAN_BLOCKS; ++i) {
            int v = blockSums[i];
            blockSums[i] = acc;
            acc += v;
        }
    }
}

__global__ __launch_bounds__(SCAN_TPB) void k_scan3(
    int* __restrict__ rowstart, const int* __restrict__ blockSums)
{
    int off = blockSums[blockIdx.x];
    int base = blockIdx.x * SCAN_EPB + threadIdx.x * SCAN_VPT;
    #pragma unroll
    for (int i = 0; i < SCAN_VPT; ++i) {
        int idx = base + i;
        if (idx < N_NODES) rowstart[idx] += off;
    }
}

// dst-range pass: writes confined to a ~2.4 MB CSR window -> L2 write-combining
__global__ __launch_bounds__(256) void k_bucket(
    const int* __restrict__ esrc, const int* __restrict__ edst,
    const float* __restrict__ ew, const int* __restrict__ rowstart,
    int* __restrict__ cursor, int2* __restrict__ csr, int lo, int hi)
{
    int e = blockIdx.x * 256 + threadIdx.x;
    if (e >= N_EDGES) return;
    int d = edst[e];
    if (d < lo || d >= hi) return;
    int p = rowstart[d] + atomicAdd(&cursor[d], 1);
    csr[p] = make_int2(esrc[e], __float_as_int(ew[e]));
}

// ---------------- node pipeline ----------------
// MFMA lin0: block = 256 nodes (4 waves x 64). Per wave: 4 node sub-tiles of 16,
// D = x[16x128] @ W0[128x64] via 16x16x32 bf16 MFMA (4 k-tiles x 4 c-tiles).
// W^T staged bf16 in LDS with XOR swizzle (b128 frag reads ~conflict-free);
// A-frags loaded straight from global (128 B/row coalesced). fp32 accumulate.
__global__ __launch_bounds__(256) void k_lin0(
    const float* __restrict__ x, const float* __restrict__ W0,
    const float* __restrict__ b0, const float* __restrict__ mw,
    const float* __restrict__ mb, u16* __restrict__ xMatB,
    float* __restrict__ r)
{
    __shared__ u16 Wt[H_ * F_IN_];   // 16 KB bf16: Wt[c*128 + (k ^ ((c&7)<<3))]
    int tid = threadIdx.x;
    for (int i = tid; i < F_IN_ * H_; i += 256) {
        int k = i >> 6, c = i & 63;              // W0[k][c] row-major
        Wt[c * F_IN_ + (k ^ ((c & 7) << 3))] = f2bf(W0[i]);
    }
    __syncthreads();

    int wave = tid >> 6, lane = tid & 63;
    int lg = lane >> 4;        // 0..3: k-block in A/B frags, node-quad in D
    int lr = lane & 15;        // A-row / B-col(channel) / D-col

    // preload B frags: 4 c-tiles x 4 k-tiles (64 VGPR)
    bf16x8 bfrag[4][4];
    float b0v[4], mwv[4];
    #pragma unroll
    for (int ct = 0; ct < 4; ++ct) {
        int c = ct * 16 + lr;
        #pragma unroll
        for (int kt = 0; kt < 4; ++kt) {
            int kidx = (kt * 32 + lg * 8) ^ ((c & 7) << 3);
            bfrag[ct][kt] = *reinterpret_cast<bf16x8*>(&Wt[c * F_IN_ + kidx]);
        }
        b0v[ct] = b0[c];
        mwv[ct] = mw[c];
    }
    float mb0 = mb[0];

    int nbase = blockIdx.x * 256 + wave * 64;
    #pragma unroll
    for (int m = 0; m < 4; ++m) {
        int arow = nbase + m * 16 + lr;
        int arowc = (arow < N_NODES) ? arow : (N_NODES - 1);   // clamp loads
        const float4* xrow = (const float4*)(x + (size_t)arowc * F_IN_);
        f32x4 acc[4];
        #pragma unroll
        for (int ct = 0; ct < 4; ++ct) {
            acc[ct][0] = b0v[ct]; acc[ct][1] = b0v[ct];
            acc[ct][2] = b0v[ct]; acc[ct][3] = b0v[ct];
        }
        #pragma unroll
        for (int kt = 0; kt < 4; ++kt) {
            int k8 = kt * 8 + lg * 2;            // float4 index of k = kt*32+lg*8
            float4 xa = xrow[k8];
            float4 xb = xrow[k8 + 1];
            bf16x8 a;
            a[0] = (short)f2bf(xa.x); a[1] = (short)f2bf(xa.y);
            a[2] = (short)f2bf(xa.z); a[3] = (short)f2bf(xa.w);
            a[4] = (short)f2bf(xb.x); a[5] = (short)f2bf(xb.y);
            a[6] = (short)f2bf(xb.z); a[7] = (short)f2bf(xb.w);
            #pragma unroll
            for (int ct = 0; ct < 4; ++ct)
                acc[ct] = __builtin_amdgcn_mfma_f32_16x16x32_bf16(
                    a, bfrag[ct][kt], acc[ct], 0, 0, 0);
        }
        // epilogue: relu, bf16 store, meta projection
        float p[4];
        #pragma unroll
        for (int reg = 0; reg < 4; ++reg) {
            int n = nbase + m * 16 + lg * 4 + reg;   // D row = lg*4+reg
            float pr = 0.f;
            #pragma unroll
            for (int ct = 0; ct < 4; ++ct) {
                float v = fmaxf(acc[ct][reg], 0.f);
                if (n < N_NODES)
                    xMatB[(size_t)n * ROW_ELEMS + ct * 16 + lr] = f2bf(v);
                pr = fmaf(v, mwv[ct], pr);
            }
            p[reg] = pr;
        }
        #pragma unroll
        for (int reg = 0; reg < 4; ++reg) {
            p[reg] += __shfl_xor(p[reg], 1, 64);
            p[reg] += __shfl_xor(p[reg], 2, 64);
            p[reg] += __shfl_xor(p[reg], 4, 64);
            p[reg] += __shfl_xor(p[reg], 8, 64);
        }
        if (lr < 4) {
            int n = nbase + m * 16 + lg * 4 + lr;
            if (n < N_NODES) r[n * LP1] = p[lr] + mb0;
        }
    }
}

// one wave per node; lanes = 16 channel-quads (ushort4) x 4 edge-quarters.
// 16 edges per iteration via 4 independent gather chains; tail slots clamp
// their broadcast index to deg-1 (weight masked to 0).
__global__ __launch_bounds__(256) void k_prop(
    const u16* __restrict__ xMatB, int l,
    const int* __restrict__ rowstart, const int* __restrict__ deg,
    const int2* __restrict__ csr,
    const float* __restrict__ mw, const float* __restrict__ mb,
    u16* __restrict__ xMatOut, float* __restrict__ r)
{
    int tid = threadIdx.x, wave = tid >> 6, lane = tid & 63;
    int n = blockIdx.x * 4 + wave;
    int sl = lane & 15, q = lane >> 4;
    int start = rowstart[n];
    int d = deg[n];
    int dm1 = (d > 0) ? (d - 1) : 0;

    int myS = 0; float myW = 0.f;
    if (lane < d) {
        int2 e = csr[start + lane];
        myS = e.x; myW = __int_as_float(e.y);
    }
    const unsigned loff = (unsigned)l * H_ + sl * 4;

    float a0x = 0.f, a0y = 0.f, a0z = 0.f, a0w = 0.f;
    float a1x = 0.f, a1y = 0.f, a1z = 0.f, a1w = 0.f;
    float a2x = 0.f, a2y = 0.f, a2z = 0.f, a2w = 0.f;
    float a3x = 0.f, a3y = 0.f, a3z = 0.f, a3w = 0.f;

    int dmax = (d < 64) ? d : 64;
    int kb = 0;
    do {
        int idx0 = kb + q;
        int idx1 = kb + q + 4;
        int idx2 = kb + q + 8;
        int idx3 = kb + q + 12;
        int ic0 = (idx0 < dm1) ? idx0 : dm1;
        int ic1 = (idx1 < dm1) ? idx1 : dm1;
        int ic2 = (idx2 < dm1) ? idx2 : dm1;
        int ic3 = (idx3 < dm1) ? idx3 : dm1;
        int   s0 = __shfl(myS, ic0, 64); float w0 = __shfl(myW, ic0, 64);
        int   s1 = __shfl(myS, ic1, 64); float w1 = __shfl(myW, ic1, 64);
        int   s2 = __shfl(myS, ic2, 64); float w2 = __shfl(myW, ic2, 64);
        int   s3 = __shfl(myS, ic3, 64); float w3 = __shfl(myW, ic3, 64);
        if (idx0 >= d) w0 = 0.f;
        if (idx1 >= d) w1 = 0.f;
        if (idx2 >= d) w2 = 0.f;
        if (idx3 >= d) w3 = 0.f;
        ushort4 v0 = *reinterpret_cast<const ushort4*>(
            &xMatB[(size_t)(unsigned)s0 * ROW_ELEMS + loff]);
        ushort4 v1 = *reinterpret_cast<const ushort4*>(
            &xMatB[(size_t)(unsigned)s1 * ROW_ELEMS + loff]);
        ushort4 v2 = *reinterpret_cast<const ushort4*>(
            &xMatB[(size_t)(unsigned)s2 * ROW_ELEMS + loff]);
        ushort4 v3 = *reinterpret_cast<const ushort4*>(
            &xMatB[(size_t)(unsigned)s3 * ROW_ELEMS + loff]);
        a0x = fmaf(bf2f(v0.x), w0, a0x); a0y = fmaf(bf2f(v0.y), w0, a0y);
        a0z = fmaf(bf2f(v0.z), w0, a0z); a0w = fmaf(bf2f(v0.w), w0, a0w);
        a1x = fmaf(bf2f(v1.x), w1, a1x); a1y = fmaf(bf2f(v1.y), w1, a1y);
        a1z = fmaf(bf2f(v1.z), w1, a1z); a1w = fmaf(bf2f(v1.w), w1, a1w);
        a2x = fmaf(bf2f(v2.x), w2, a2x); a2y = fmaf(bf2f(v2.y), w2, a2y);
        a2z = fmaf(bf2f(v2.z), w2, a2z); a2w = fmaf(bf2f(v2.w), w2, a2w);
        a3x = fmaf(bf2f(v3.x), w3, a3x); a3y = fmaf(bf2f(v3.y), w3, a3y);
        a3z = fmaf(bf2f(v3.z), w3, a3z); a3w = fmaf(bf2f(v3.w), w3, a3w);
        kb += 16;
    } while (kb < dmax);

    // fallback deg > 64 (statistically never for Poisson(14.1))
    for (int kb2 = 64; kb2 < d; kb2 += 16) {
        #pragma unroll
        for (int j = 0; j < 4; ++j) {
            int idx = kb2 + j * 4 + q;
            if (idx < d) {
                int2 e = csr[start + idx];
                float w = __int_as_float(e.y);
                ushort4 v = *reinterpret_cast<const ushort4*>(
                    &xMatB[(size_t)(unsigned)e.x * ROW_ELEMS + loff]);
                a0x = fmaf(bf2f(v.x), w, a0x);
                a0y = fmaf(bf2f(v.y), w, a0y);
                a0z = fmaf(bf2f(v.z), w, a0z);
                a0w = fmaf(bf2f(v.w), w, a0w);
            }
        }
    }

    float r0 = a0x + a1x + a2x + a3x;
    float r1 = a0y + a1y + a2y + a3y;
    float r2 = a0z + a1z + a2z + a3z;
    float r3 = a0w + a1w + a2w + a3w;
    r0 += __shfl_xor(r0, 16, 64); r0 += __shfl_xor(r0, 32, 64);
    r1 += __shfl_xor(r1, 16, 64); r1 += __shfl_xor(r1, 32, 64);
    r2 += __shfl_xor(r2, 16, 64); r2 += __shfl_xor(r2, 32, 64);
    r3 += __shfl_xor(r3, 16, 64); r3 += __shfl_xor(r3, 32, 64);
    r0 = fmaxf(r0, 0.f); r1 = fmaxf(r1, 0.f);
    r2 = fmaxf(r2, 0.f); r3 = fmaxf(r3, 0.f);
    if (q == 0) {
        ushort4 o; o.x = f2bf(r0); o.y = f2bf(r1); o.z = f2bf(r2); o.w = f2bf(r3);
        *reinterpret_cast<ushort4*>(
            &xMatOut[(size_t)n * ROW_ELEMS + (l + 1) * H_ + sl * 4]) = o;
    }
    float dot = r0 * mw[4 * sl] + r1 * mw[4 * sl + 1] +
                r2 * mw[4 * sl + 2] + r3 * mw[4 * sl + 3];
    dot += __shfl_xor(dot, 1, 64);
    dot += __shfl_xor(dot, 2, 64);
    dot += __shfl_xor(dot, 4, 64);
    dot += __shfl_xor(dot, 8, 64);
    if (lane == 0) r[n * LP1 + (l + 1)] = dot + mb[0];
}

// one THREAD per node: stick-breaking t, entropy, gumbel-softmax weights tM
__global__ __launch_bounds__(256) void k_gate(
    const float* __restrict__ r, const float* __restrict__ gum,
    float* __restrict__ tM, float* __restrict__ entPart)
{
    __shared__ float lds[4];
    int tid = threadIdx.x;
    int n = blockIdx.x * 256 + tid;
    float ent = 0.f;
    if (n < N_NODES) {
        float t[LP1], lg[LP1];
        float cp = 1.f;
        #pragma unroll
        for (int j = 0; j < LP1; ++j) {
            float rv = r[n * LP1 + j];
            float s = 1.f / (1.f + expf(-rv));
            t[j] = (j == L_LAYERS) ? cp : s * cp;
            cp *= (1.f - s);
        }
        float mx = -INFINITY;
        #pragma unroll
        for (int j = 0; j < LP1; ++j) {
            float lt = logf(t[j] + EPS_T);
            ent -= t[j] * lt;
            lg[j] = lt + gum[n * LP1 + j];
            mx = fmaxf(mx, lg[j]);
        }
        float se = 0.f;
        #pragma unroll
        for (int j = 0; j < LP1; ++j) { lg[j] = expf(lg[j] - mx); se += lg[j]; }
        float inv = 1.f / se;
        #pragma unroll
        for (int j = 0; j < LP1; ++j) tM[n * LP1 + j] = lg[j] * inv;
    }
    float s = waveReduceSum(ent);
    int wave = tid >> 6, lane = tid & 63;
    if (lane == 0) lds[wave] = s;
    __syncthreads();
    if (tid == 0) entPart[blockIdx.x] = lds[0] + lds[1] + lds[2] + lds[3];
}

// per node (1 wave): mix xMat with tM, lin1, log_softmax
__global__ __launch_bounds__(256) void k_final(
    const u16* __restrict__ xMatB, const float* __restrict__ tM,
    const float* __restrict__ W1, const float* __restrict__ b1,
    float* __restrict__ out)
{
    __shared__ float mixLds[4][H_];
    int tid = threadIdx.x, wave = tid >> 6, lane = tid & 63;
    int n = blockIdx.x * 4 + wave;
    float tm = (lane < LP1) ? tM[n * LP1 + lane] : 0.f;
    float m = 0.f;
    #pragma unroll
    for (int j = 0; j < LP1; ++j) {
        float w = __shfl(tm, j, 64);
        m = fmaf(w, bf2f(xMatB[(size_t)n * ROW_ELEMS + j * H_ + lane]), m);
    }
    mixLds[wave][lane] = m;
    __syncthreads();
    float o = -INFINITY;
    if (lane < C_OUT) {
        float a = b1[lane];
        #pragma unroll 8
        for (int h = 0; h < H_; ++h)
            a = fmaf(mixLds[wave][h], W1[h * C_OUT + lane], a);
        o = a;
    }
    float omx = waveReduceMax(o);
    float ex = (lane < C_OUT) ? expf(o - omx) : 0.f;
    float es = waveReduceSum(ex);
    if (lane < C_OUT)
        out[(size_t)n * C_OUT + lane] = o - omx - logf(es);
}

__global__ __launch_bounds__(256) void k_entreduce(
    const float* __restrict__ part, int n, float scale, float* __restrict__ out)
{
    __shared__ float lds[4];
    int tid = threadIdx.x;
    float s = 0.f;
    for (int i = tid; i < n; i += 256) s += part[i];
    s = waveReduceSum(s);
    int wave = tid >> 6, lane = tid & 63;
    if (lane == 0) lds[wave] = s;
    __syncthreads();
    if (tid == 0) out[0] = (lds[0] + lds[1] + lds[2] + lds[3]) * scale;
}

extern "C" void kernel_launch(void* const* d_in, const int* in_sizes, int n_in,
                              void* d_out, int out_size, void* d_ws, size_t ws_size,
                              hipStream_t stream)
{
    const float* x   = (const float*)d_in[0];
    const float* ew  = (const float*)d_in[1];
    const float* gum = (const float*)d_in[2];
    const float* W0  = (const float*)d_in[3];
    const float* b0  = (const float*)d_in[4];
    const float* mw  = (const float*)d_in[5];
    const float* mb  = (const float*)d_in[6];
    const float* W1  = (const float*)d_in[7];
    const float* b1  = (const float*)d_in[8];
    const int* esrc  = (const int*)d_in[9];
    const int* edst  = (const int*)d_in[10];
    float* out = (float*)d_out;

    const size_t xMatBytes = (size_t)N_NODES * ROW_ELEMS * sizeof(u16); // 195,840,000
    const size_t rBytes    = (size_t)N_NODES * LP1 * sizeof(float);
    const size_t tMBytes   = (size_t)N_NODES * LP1 * sizeof(float);
    const size_t entBytes  = (size_t)((N_NODES + 255) / 256) * sizeof(float);
    const size_t degBytes  = (size_t)N_NODES * sizeof(int);
    const size_t curBytes  = (size_t)N_NODES * sizeof(int);
    const size_t rowBytes  = (size_t)N_NODES * sizeof(int);
    const size_t bsBytes   = 512;
    const size_t csrBytes  = (size_t)N_EDGES * sizeof(int2);            //  19,200,000
    const size_t need = xMatBytes + rBytes + tMBytes + entBytes + degBytes +
                        curBytes + rowBytes + bsBytes + csrBytes;       // ~229.6 MB
    if (ws_size < need) return;

    char* p = (char*)d_ws;
    u16*  xMatB    = (u16*)p;           p += xMatBytes;
    float* rbuf    = (float*)p;         p += rBytes;
    float* tMbuf   = (float*)p;         p += tMBytes;
    float* entP    = (float*)p;         p += entBytes;
    int*  deg      = (int*)p;           p += degBytes;
    int*  cursor   = (int*)p;           p += curBytes;   // deg+cursor zeroed together
    int*  rowstart = (int*)p;           p += rowBytes;
    int*  blockSums= (int*)p;           p += bsBytes;
    int2* csr      = (int2*)p;

    const int nodeBlocks = N_NODES / 4;                 // 42500 (exact)
    const int edgeBlocks = (N_EDGES + 255) / 256;       // 9375 (exact)
    const int gateBlocks = (N_NODES + 255) / 256;       // 665
    const int lin0Blocks = (N_NODES + 255) / 256;       // 665 (256 nodes/block)

    // CSR build  (k_zero4 tail spills into rowstart; scan rewrites it fully)
    k_zero4<<<333, 256, 0, stream>>>((float4*)deg);
    k_hist<<<edgeBlocks, 256, 0, stream>>>(edst, deg);
    k_scan1<<<SCAN_BLOCKS, SCAN_TPB, 0, stream>>>(deg, rowstart, blockSums);
    k_scan2<<<1, 64, 0, stream>>>(blockSums);
    k_scan3<<<SCAN_BLOCKS, SCAN_TPB, 0, stream>>>(rowstart, blockSums);
    const int STEP = N_NODES / 8;                       // 21250
    for (int i = 0; i < 8; ++i)
        k_bucket<<<edgeBlocks, 256, 0, stream>>>(esrc, edst, ew, rowstart,
                                                 cursor, csr, i * STEP,
                                                 (i + 1) * STEP);

    // node pipeline
    k_lin0<<<lin0Blocks, 256, 0, stream>>>(x, W0, b0, mw, mb, xMatB, rbuf);
    for (int l = 0; l < L_LAYERS; ++l)
        k_prop<<<nodeBlocks, 256, 0, stream>>>(xMatB, l, rowstart, deg, csr,
                                               mw, mb, xMatB, rbuf);
    k_gate<<<gateBlocks, 256, 0, stream>>>(rbuf, gum, tMbuf, entP);
    k_final<<<nodeBlocks, 256, 0, stream>>>(xMatB, tMbuf, W1, b1, out);
    k_entreduce<<<1, 256, 0, stream>>>(entP, gateBlocks, 1.0f / N_NODES,
                                       out + (size_t)N_NODES * C_OUT);
}